// Round 5
// baseline (2025.278 us; speedup 1.0000x reference)
//
#include <hip/hip_runtime.h>

typedef short bf16x8 __attribute__((ext_vector_type(8)));
typedef float f32x4 __attribute__((ext_vector_type(4)));
typedef unsigned short us;

#define BN_EPS 1e-3f

// fp32 -> bf16 round-to-nearest-even (no NaN inputs in this net)
static __device__ __forceinline__ us f2bs(float x) {
  unsigned int u = __builtin_bit_cast(unsigned int, x);
  unsigned int r = (u + 0x7FFFu + ((u >> 16) & 1u)) >> 16;
  return (us)r;
}

// async global->LDS, 16B per lane; LDS dest is wave-uniform base + lane*16.
static __device__ __forceinline__ void gl_lds16(const us* g, us* l) {
  __builtin_amdgcn_global_load_lds(
      (const __attribute__((address_space(1))) void*)g,
      (__attribute__((address_space(3))) void*)l, 16, 0, 0);
}

// ---------------- transpose + fp32->bf16: src [K,N] f32 -> dst [N,K] bf16 ----
__global__ __launch_bounds__(256) void transpose_bf16(
    const float* __restrict__ src, us* __restrict__ dst, int K, int N,
    long sstride, long dstride) {
  long sbs = (long)blockIdx.z * sstride;
  long sbd = (long)blockIdx.z * dstride;
  __shared__ float tile[32][33];
  int tx = threadIdx.x & 31, ty = threadIdx.x >> 5;  // 32 x 8
  int k0 = blockIdx.x * 32, n0 = blockIdx.y * 32;
  for (int i = 0; i < 32; i += 8)
    tile[ty + i][tx] = src[sbs + (long)(k0 + ty + i) * N + n0 + tx];
  __syncthreads();
  for (int i = 0; i < 32; i += 8)
    dst[sbd + (long)(n0 + ty + i) * K + k0 + tx] = f2bs(tile[tx][ty + i]);
}

// ---------------- embedding: h = state @ Wemb + bemb + pes; hb = bf16(h) ----
__global__ __launch_bounds__(256) void embed_kernel(
    const float* __restrict__ state, const float* __restrict__ Wemb,
    const float* __restrict__ bemb, const float* __restrict__ pes,
    float* __restrict__ h, us* __restrict__ hb) {
  int t = threadIdx.x;
  int row0 = blockIdx.x * 8;
  __shared__ float st[8][64];
  {
    int i = t;
    st[i >> 6][i & 63] = state[(long)row0 * 64 + i];
    i += 256;
    st[i >> 6][i & 63] = state[(long)row0 * 64 + i];
  }
  __syncthreads();
  int c0 = t, c1 = t + 256;
  float acc0[8], acc1[8];
#pragma unroll
  for (int r = 0; r < 8; ++r) { acc0[r] = 0.f; acc1[r] = 0.f; }
  for (int kk = 0; kk < 64; ++kk) {
    float w0 = Wemb[kk * 512 + c0], w1 = Wemb[kk * 512 + c1];
#pragma unroll
    for (int r = 0; r < 8; ++r) {
      acc0[r] += st[r][kk] * w0;
      acc1[r] += st[r][kk] * w1;
    }
  }
  float be0 = bemb[c0], be1 = bemb[c1];
#pragma unroll
  for (int r = 0; r < 8; ++r) {
    int row = row0 + r, s = row & 255;
    float v0 = acc0[r] + be0 + pes[(long)s * 512 + c0];
    float v1 = acc1[r] + be1 + pes[(long)s * 512 + c1];
    h[(long)row * 512 + c0] = v0;
    h[(long)row * 512 + c1] = v1;
    hb[(long)row * 512 + c0] = f2bs(v0);
    hb[(long)row * 512 + c1] = f2bs(v1);
  }
}

// ---------------- generic bf16 MFMA GEMM, B given transposed [N,K] ----------
// Staging: global_load_lds width=16, linear LDS [BM][64] (BK=64), 2-barrier
// K-loop (m97 structure).
enum { EPI_QKV = 0, EPI_RESID_F32 = 1, EPI_RELU_BF16 = 2, EPI_FFN2_F32 = 3,
       EPI_FEAT = 4 };

template <int BM, int BN, int WM, int WN, int EPI>
__global__ __launch_bounds__((BM / WM) * (BN / WN) * 64)
void gemm_bt(const us* __restrict__ A, int lda, long batchA,
             const us* __restrict__ Bt, int ldb, long batchB,
             void* __restrict__ Cout, void* __restrict__ C2,
             void* __restrict__ C3, int ldc,
             const float* __restrict__ bias,
             const float* __restrict__ resid,
             const float* __restrict__ gsum, const float* __restrict__ gsumsq,
             const float* __restrict__ gamma, const float* __restrict__ beta,
             int K) {
  constexpr int WCols = BN / WN;
  constexpr int NT = (BM / WM) * (BN / WN) * 64;
  constexpr int NW = NT / 64;
  constexpr int MI = WM / 16, NI = WN / 16;
  constexpr int LA = BM / 8;  // 1KB wave-loads to fill A tile (8 rows each)
  constexpr int LB = BN / 8;
  const int tid = threadIdx.x;
  const int w = tid >> 6, l = tid & 63;
  const int wr = w / WCols, wc = w % WCols;
  const int lr = l & 15, lh = l >> 4;
  const int z = blockIdx.z;
  const long m0 = (long)blockIdx.x * BM;
  const long n0 = (long)blockIdx.y * BN;
  A += (long)z * batchA;
  Bt += (long)z * batchB;
  __shared__ __align__(16) us As[BM][64];
  __shared__ __align__(16) us Bs[BN][64];
  // per-lane source offsets for the async staging loads
  const int srow = l >> 3, scol = (l & 7) << 3;
  f32x4 acc[MI][NI] = {};
  for (int kt = 0; kt < K; kt += 64) {
    __syncthreads();  // previous tile's reads complete before overwrite
    for (int j = w; j < LA; j += NW) {
      int rb = j * 8;
      gl_lds16(A + (m0 + rb + srow) * lda + kt + scol, &As[rb][0]);
    }
    for (int j = w; j < LB; j += NW) {
      int rb = j * 8;
      gl_lds16(Bt + (n0 + rb + srow) * ldb + kt + scol, &Bs[rb][0]);
    }
    asm volatile("s_waitcnt vmcnt(0)" ::: "memory");
    __syncthreads();
#pragma unroll
    for (int kk = 0; kk < 64; kk += 32) {
      bf16x8 af[MI], bfr[NI];
#pragma unroll
      for (int mi = 0; mi < MI; ++mi)
        af[mi] = *(const bf16x8*)&As[wr * WM + mi * 16 + lr][kk + lh * 8];
#pragma unroll
      for (int ni = 0; ni < NI; ++ni)
        bfr[ni] = *(const bf16x8*)&Bs[wc * WN + ni * 16 + lr][kk + lh * 8];
#pragma unroll
      for (int mi = 0; mi < MI; ++mi)
#pragma unroll
        for (int ni = 0; ni < NI; ++ni)
          acc[mi][ni] = __builtin_amdgcn_mfma_f32_16x16x32_bf16(
              af[mi], bfr[ni], acc[mi][ni], 0, 0, 0);
    }
  }
#pragma unroll
  for (int mi = 0; mi < MI; ++mi) {
#pragma unroll
    for (int ni = 0; ni < NI; ++ni) {
      const int col = (int)n0 + wc * WN + ni * 16 + lr;
      float bv_ = 0.f;
      int segc = col;
      if constexpr (EPI == EPI_QKV) {
        int seg = col >> 9;
        segc = col & 511;
        bv_ = seg == 0 ? bias[segc] : (seg == 1 ? gamma[segc] : beta[segc]);
      } else if constexpr (EPI != EPI_FEAT) {
        bv_ = bias[col];
      }
      float aa = 0.f, bb2 = 0.f;
      if constexpr (EPI == EPI_FFN2_F32) {
        const float invN = 1.f / 16384.f;
        float mu = gsum[col] * invN;
        float var = gsumsq[col] * invN - mu * mu;
        aa = gamma[col] * rsqrtf(var + BN_EPS);
        bb2 = beta[col] - mu * aa;
      }
#pragma unroll
      for (int q_ = 0; q_ < 4; ++q_) {
        const long row = m0 + wr * WM + mi * 16 + lh * 4 + q_;
        float v = acc[mi][ni][q_] + bv_;
        if constexpr (EPI == EPI_QKV) {
          int seg = col >> 9;
          if (seg == 0) {
            ((us*)Cout)[row * 512 + segc] = f2bs(v);
          } else if (seg == 1) {
            ((us*)C2)[row * 512 + segc] = f2bs(v);
          } else {  // V, store transposed [b][h][dh][s]
            long o = (((row >> 8) * 8 + (segc >> 6)) * 64 + (segc & 63)) * 256 +
                     (row & 255);
            ((us*)C3)[o] = f2bs(v);
          }
        } else if constexpr (EPI == EPI_RESID_F32) {
          ((float*)Cout)[row * ldc + col] = v + resid[row * ldc + col];
        } else if constexpr (EPI == EPI_RELU_BF16) {
          ((us*)Cout)[row * ldc + col] = f2bs(fmaxf(v, 0.f));
        } else if constexpr (EPI == EPI_FEAT) {
          atomicAdd(&((float*)Cout)[row * ldc + col], v);
        } else {  // EPI_FFN2_F32: z = (y*a+b) + acc + bias
          float ybn = resid[row * ldc + col] * aa + bb2;
          ((float*)Cout)[row * ldc + col] = ybn + v;
        }
      }
    }
  }
}

// ---------------- fused attention: QK^T*scale + softmax + PV -> ctx ---------
// grid (S/32, B*H); 32 q-rows per block. P kept in LDS (bf16, identical
// rounding to the old probs path); V^T staged in the K buffer for PV.
__global__ __launch_bounds__(256) void attn_kernel(
    const us* __restrict__ q, const us* __restrict__ k,
    const us* __restrict__ vt, us* __restrict__ ctx) {
  const int qb = blockIdx.x;  // 0..7
  const int z = blockIdx.y;   // b*8+h
  const int b = z >> 3, hh = z & 7;
  const long qkBase = (long)b * 131072 + hh * 64;
  const int tid = threadIdx.x, w = tid >> 6, l = tid & 63;
  const int lr = l & 15, lh = l >> 4;
  __shared__ __align__(16) us Qs[32][72];
  __shared__ __align__(16) us Ks[64][72];  // reused as V staging in PV phase
  __shared__ float Sc[32][260];
  __shared__ __align__(16) us Pb[32][264];
  __shared__ float red[32][8];
  __shared__ float rowmax[32], rowsum[32];
  {
    int r = tid >> 3, c = (tid & 7) << 3;
    *(uint4*)&Qs[r][c] =
        *(const uint4*)(q + qkBase + (long)(qb * 32 + r) * 512 + c);
  }
  const int qr = (w >> 1) * 16, qc = (w & 1) * 32;
  for (int skb = 0; skb < 4; ++skb) {
    __syncthreads();
    for (int i = tid; i < 512; i += 256) {
      int r = i >> 3, c = (i & 7) << 3;
      *(uint4*)&Ks[r][c] =
          *(const uint4*)(k + qkBase + (long)(skb * 64 + r) * 512 + c);
    }
    __syncthreads();
    f32x4 sacc[2] = {};
#pragma unroll
    for (int kh = 0; kh < 2; ++kh) {
      bf16x8 aq = *(const bf16x8*)&Qs[qr + lr][kh * 32 + lh * 8];
#pragma unroll
      for (int ni = 0; ni < 2; ++ni) {
        bf16x8 bkk = *(const bf16x8*)&Ks[qc + ni * 16 + lr][kh * 32 + lh * 8];
        sacc[ni] = __builtin_amdgcn_mfma_f32_16x16x32_bf16(aq, bkk, sacc[ni], 0, 0, 0);
      }
    }
#pragma unroll
    for (int ni = 0; ni < 2; ++ni)
#pragma unroll
      for (int qq = 0; qq < 4; ++qq)
        Sc[qr + lh * 4 + qq][skb * 64 + qc + ni * 16 + lr] =
            sacc[ni][qq] * 0.125f;
  }
  __syncthreads();
  {
    int r = tid >> 3, p = tid & 7;
    float m = -1e30f;
    for (int j = 0; j < 32; ++j) m = fmaxf(m, Sc[r][p * 32 + j]);
    red[r][p] = m;
  }
  __syncthreads();
  if (tid < 32) {
    float m = red[tid][0];
    for (int p = 1; p < 8; ++p) m = fmaxf(m, red[tid][p]);
    rowmax[tid] = m;
  }
  __syncthreads();
  {
    int r = tid >> 3, p = tid & 7;
    float m = rowmax[r], s = 0.f;
    for (int j = 0; j < 32; ++j) {
      float e = __expf(Sc[r][p * 32 + j] - m);
      Sc[r][p * 32 + j] = e;
      s += e;
    }
    red[r][p] = s;
  }
  __syncthreads();
  if (tid < 32) {
    float s = 0.f;
    for (int p = 0; p < 8; ++p) s += red[tid][p];
    rowsum[tid] = 1.f / s;
  }
  __syncthreads();
  // P -> LDS bf16 (same rounding as the old global probs path)
  for (int it = 0; it < 32; ++it)
    Pb[it][tid] = f2bs(Sc[it][tid] * rowsum[it]);
  // PV: C[32 q][64 d] = P[32][256] x V[256][64], via V^T tiles [d][s]
  const us* vb = vt + (long)z * 16384;
  f32x4 pacc[2] = {};
  for (int kc = 0; kc < 256; kc += 64) {
    __syncthreads();  // Pb visible (kc==0); prior Vs reads done (kc>0)
    for (int i = tid; i < 512; i += 256) {
      int r = i >> 3, c = (i & 7) << 3;
      *(uint4*)&Ks[r][c] = *(const uint4*)(vb + (long)r * 256 + kc + c);
    }
    __syncthreads();
#pragma unroll
    for (int kh = 0; kh < 2; ++kh) {
      bf16x8 ap = *(const bf16x8*)&Pb[qr + lr][kc + kh * 32 + lh * 8];
#pragma unroll
      for (int ni = 0; ni < 2; ++ni) {
        bf16x8 bv2 = *(const bf16x8*)&Ks[qc + ni * 16 + lr][kh * 32 + lh * 8];
        pacc[ni] = __builtin_amdgcn_mfma_f32_16x16x32_bf16(ap, bv2, pacc[ni], 0, 0, 0);
      }
    }
  }
  const long cb2 = ((long)(b * 256 + qb * 32)) * 512 + hh * 64;
#pragma unroll
  for (int ni = 0; ni < 2; ++ni)
#pragma unroll
    for (int q_ = 0; q_ < 4; ++q_) {
      int row = qr + lh * 4 + q_;
      int col = qc + ni * 16 + lr;
      ctx[cb2 + (long)row * 512 + col] = f2bs(pacc[ni][q_]);
    }
}

// ---------------- BN stats / apply ------------------------------------------
__global__ __launch_bounds__(256) void bn_stats(const float* __restrict__ y,
                                                float* __restrict__ gsum,
                                                float* __restrict__ gsumsq) {
  int t = threadIdx.x;
  long base = (long)blockIdx.x * 64 * 512;
  float s0 = 0, q0 = 0, s1 = 0, q1 = 0;
  for (int r = 0; r < 64; ++r) {
    float v0 = y[base + r * 512 + t];
    float v1 = y[base + r * 512 + t + 256];
    s0 += v0; q0 += v0 * v0;
    s1 += v1; q1 += v1 * v1;
  }
  atomicAdd(&gsum[t], s0);
  atomicAdd(&gsumsq[t], q0);
  atomicAdd(&gsum[t + 256], s1);
  atomicAdd(&gsumsq[t + 256], q1);
}

__global__ __launch_bounds__(256) void bn_apply(
    const float* __restrict__ y, const float* __restrict__ gsum,
    const float* __restrict__ gsumsq, const float* __restrict__ gamma,
    const float* __restrict__ beta, us* __restrict__ ybb) {
  long i4 = (long)blockIdx.x * 256 + threadIdx.x;
  long e = i4 * 4;
  int c = (int)(e & 511);
  const float invN = 1.f / 16384.f;
  float4 v = *(const float4*)(y + e);
  float vv[4] = {v.x, v.y, v.z, v.w};
  ushort4 r;
  us* rp = (us*)&r;
#pragma unroll
  for (int j = 0; j < 4; ++j) {
    int cj = c + j;
    float mu = gsum[cj] * invN;
    float var = gsumsq[cj] * invN - mu * mu;
    float a = gamma[cj] * rsqrtf(var + BN_EPS);
    float b = beta[cj] - mu * a;
    rp[j] = f2bs(vv[j] * a + b);
  }
  *(ushort4*)(ybb + e) = r;
}

// ---------------- LayerNorm per row -> h (f32) + hb (bf16) ------------------
__global__ __launch_bounds__(128) void ln_kernel(
    const float* __restrict__ zin, const float* __restrict__ g,
    const float* __restrict__ b, float* __restrict__ hout,
    us* __restrict__ hb) {
  int r = blockIdx.x, t = threadIdx.x;
  const float* zr = zin + (long)r * 512;
  float4 v = *(const float4*)(zr + t * 4);
  float s = v.x + v.y + v.z + v.w;
  float qs = v.x * v.x + v.y * v.y + v.z * v.z + v.w * v.w;
  for (int off = 32; off >= 1; off >>= 1) {
    s += __shfl_down(s, off);
    qs += __shfl_down(qs, off);
  }
  __shared__ float ls[2], lq[2];
  if ((t & 63) == 0) {
    ls[t >> 6] = s;
    lq[t >> 6] = qs;
  }
  __syncthreads();
  float mu = (ls[0] + ls[1]) * (1.f / 512.f);
  float var = (lq[0] + lq[1]) * (1.f / 512.f) - mu * mu;
  float rs = rsqrtf(var + BN_EPS);
  float4 gg = *(const float4*)(g + t * 4);
  float4 bb = *(const float4*)(b + t * 4);
  float o0 = gg.x * (v.x - mu) * rs + bb.x;
  float o1 = gg.y * (v.y - mu) * rs + bb.y;
  float o2 = gg.z * (v.z - mu) * rs + bb.z;
  float o3 = gg.w * (v.w - mu) * rs + bb.w;
  *(float4*)(hout + (long)r * 512 + t * 4) = make_float4(o0, o1, o2, o3);
  ushort4 hv;
  us* hp = (us*)&hv;
  hp[0] = f2bs(o0); hp[1] = f2bs(o1); hp[2] = f2bs(o2); hp[3] = f2bs(o3);
  *(ushort4*)(hb + (long)r * 512 + t * 4) = hv;
}

// ---------------- head ------------------------------------------------------
__global__ void zerof(float* __restrict__ p, int n) {
  int i = blockIdx.x * 256 + threadIdx.x;
  if (i < n) p[i] = 0.f;
}

__global__ __launch_bounds__(320) void final_head(
    const float* __restrict__ feat, const float* __restrict__ bf_,
    const float* __restrict__ action, const float* __restrict__ Wfin,
    const float* __restrict__ bfin, float* __restrict__ out) {
  int t = threadIdx.x;
  int b = t & 63, o = t >> 6;  // 64 x 5
  float acc = bfin[o];
  for (int j = 0; j < 32; ++j) acc += (feat[b * 32 + j] + bf_[j]) * Wfin[j * 5 + o];
  for (int j = 0; j < 8; ++j) acc += action[b * 8 + j] * Wfin[(32 + j) * 5 + o];
  out[b * 5 + o] = acc;
}

// ---------------- host ------------------------------------------------------
extern "C" void kernel_launch(void* const* d_in, const int* in_sizes, int n_in,
                              void* d_out, int out_size, void* d_ws,
                              size_t ws_size, hipStream_t stream) {
  const float* state = (const float*)d_in[0];
  const float* action = (const float*)d_in[1];
  const float* pes = (const float*)d_in[2];
  const float* W_emb = (const float*)d_in[3];
  const float* b_emb = (const float*)d_in[4];
  const float* Wq = (const float*)d_in[5];
  const float* bq = (const float*)d_in[6];
  const float* Wk = (const float*)d_in[7];
  const float* bk = (const float*)d_in[8];
  const float* Wv = (const float*)d_in[9];
  const float* bv = (const float*)d_in[10];
  const float* Wo = (const float*)d_in[11];
  const float* bo = (const float*)d_in[12];
  const float* bn_g = (const float*)d_in[13];
  const float* bn_b = (const float*)d_in[14];
  const float* W1 = (const float*)d_in[15];
  const float* b1 = (const float*)d_in[16];
  const float* W2 = (const float*)d_in[17];
  const float* b2 = (const float*)d_in[18];
  const float* ln_g = (const float*)d_in[19];
  const float* ln_b = (const float*)d_in[20];
  const float* Wf = (const float*)d_in[21];
  const float* bf_ = (const float*)d_in[22];
  const float* Wfin = (const float*)d_in[23];
  const float* bfin = (const float*)d_in[24];
  float* out = (float*)d_out;
  (void)in_sizes; (void)n_in; (void)out_size;

  char* wp = (char*)d_ws;
  size_t off = 0;
  auto take = [&](size_t bytes) {
    void* p = wp + off;
    off += (bytes + 255) & ~(size_t)255;
    return p;
  };
  // Persistent across the whole launch:
  us* qkvT = (us*)take(6ull * 1536 * 512 * 2);  // [l][{q,k,v}*512][512]
  us* WoT = (us*)take(6ull * 512 * 512 * 2);
  us* W1T = (us*)take(6ull * 2048 * 512 * 2);
  us* W2T = (us*)take(6ull * 512 * 2048 * 2);
  us* WfT = (us*)take(32ull * 131072 * 2);      // [32][131072]
  float* h = (float*)take(16384ull * 512 * 4);   // f32 activations (resid)
  us* hb = (us*)take(16384ull * 512 * 2);        // bf16 copy of h
  float* y = (float*)take(16384ull * 512 * 4);   // attn-block output (pre-BN)
  // Aliased regions (lifetime analysis; all transitions write-after-last-read
  // on the same stream):
  //   R1: q -> z[0:8M)     R2: k -> y_bn(bf16) -> z[8M:16M)
  //   R3: vT               R4: ctx -> ffn hidden f1
  us* qb_ = (us*)take(16384ull * 512 * 2);       // R1
  us* kb_ = (us*)take(16384ull * 512 * 2);       // R2 (contiguous after R1)
  us* vt = (us*)take(16384ull * 512 * 2);        // R3
  us* bigR4 = (us*)take(33554432ull * 2);        // R4
  float* gsum = (float*)take(512 * 4);
  float* gsumsq = (float*)take(512 * 4);
  float* feat = (float*)take(2048 * 4);
  us* ctxb = bigR4;        // R4 (ctx live attn -> Wo; must NOT alias q/k/vt:
                           //     fused attn reads q,k,vt while writing ctx)
  us* f1 = bigR4;          // R4 reuse (ctx dead after Wo; f1 written by FFN1)
  us* ybb = kb_;           // alias R2 (k dead after attn_kernel)
  float* zb = (float*)qb_; // alias R1+R2 (q dead after attn, ybb dead after FFN1)

  // Workspace guard: clean diagnostic failure instead of GPU fault if pool
  // is smaller than planned.
  if (off > ws_size) return;

  transpose_bf16<<<dim3(16, 16, 6), 256, 0, stream>>>(Wq, qkvT, 512, 512,
                                                      262144, 786432);
  transpose_bf16<<<dim3(16, 16, 6), 256, 0, stream>>>(Wk, qkvT + 262144, 512,
                                                      512, 262144, 786432);
  transpose_bf16<<<dim3(16, 16, 6), 256, 0, stream>>>(Wv, qkvT + 524288, 512,
                                                      512, 262144, 786432);
  transpose_bf16<<<dim3(16, 16, 6), 256, 0, stream>>>(Wo, WoT, 512, 512,
                                                      262144, 262144);
  transpose_bf16<<<dim3(16, 64, 6), 256, 0, stream>>>(W1, W1T, 512, 2048,
                                                      1048576, 1048576);
  transpose_bf16<<<dim3(64, 16, 6), 256, 0, stream>>>(W2, W2T, 2048, 512,
                                                      1048576, 1048576);
  transpose_bf16<<<dim3(4096, 1, 1), 256, 0, stream>>>(Wf, WfT, 131072, 32,
                                                       0, 0);
  embed_kernel<<<2048, 256, 0, stream>>>(state, W_emb, b_emb, pes, h, hb);

  for (int l = 0; l < 6; ++l) {
    const us* qkvTl = qkvT + (size_t)l * 786432;
    const us* WoTl = WoT + (size_t)l * 262144;
    const us* W1Tl = W1T + (size_t)l * 1048576;
    const us* W2Tl = W2T + (size_t)l * 1048576;

    // fused QKV: N=1536, writes q, k, and v-transposed in one pass
    gemm_bt<128, 128, 64, 64, EPI_QKV><<<dim3(128, 12, 1), 256, 0, stream>>>(
        hb, 512, 0, qkvTl, 512, 0, qb_, kb_, vt, 512, bq + l * 512,
        nullptr, nullptr, nullptr, bk + l * 512, bv + l * 512, 512);
    // fused attention: QK^T + softmax + PV -> ctx
    attn_kernel<<<dim3(8, 512), 256, 0, stream>>>(qb_, kb_, vt, ctxb);
    gemm_bt<128, 128, 64, 64, EPI_RESID_F32><<<dim3(128, 4, 1), 256, 0, stream>>>(
        ctxb, 512, 0, WoTl, 512, 0, y, nullptr, nullptr, 512, bo + l * 512,
        h, nullptr, nullptr, nullptr, nullptr, 512);
    zerof<<<4, 256, 0, stream>>>(gsum, 1024);  // gsum+gsumsq contiguous
    bn_stats<<<256, 256, 0, stream>>>(y, gsum, gsumsq);
    bn_apply<<<8192, 256, 0, stream>>>(y, gsum, gsumsq, bn_g + l * 512,
                                       bn_b + l * 512, ybb);
    gemm_bt<128, 128, 64, 64, EPI_RELU_BF16><<<dim3(128, 16, 1), 256, 0, stream>>>(
        ybb, 512, 0, W1Tl, 512, 0, f1, nullptr, nullptr, 2048, b1 + l * 2048,
        nullptr, nullptr, nullptr, nullptr, nullptr, 512);
    gemm_bt<128, 128, 64, 64, EPI_FFN2_F32><<<dim3(128, 4, 1), 256, 0, stream>>>(
        f1, 2048, 0, W2Tl, 2048, 0, zb, nullptr, nullptr, 512, b2 + l * 512,
        y, gsum, gsumsq, bn_g + l * 512, bn_b + l * 512, 2048);
    ln_kernel<<<16384, 128, 0, stream>>>(zb, ln_g + l * 512, ln_b + l * 512, h, hb);
  }

  // feat = flat @ Wf: plain GEMM M=64,N=32,K=131072 (flat rows are contiguous
  // hb slices), split-K over 128 chunks of 1024, fp32 atomic accumulate.
  zerof<<<8, 256, 0, stream>>>(feat, 2048);
  gemm_bt<64, 32, 32, 16, EPI_FEAT><<<dim3(1, 1, 128), 256, 0, stream>>>(
      hb, 131072, 1024, WfT, 131072, 1024, feat, nullptr, nullptr, 32,
      nullptr, nullptr, nullptr, nullptr, nullptr, nullptr, 1024);
  final_head<<<1, 320, 0, stream>>>(feat, bf_, action, Wfin, bfin, out);
}

// Round 6
// 1872.346 us; speedup vs baseline: 1.0817x; 1.0817x over previous
//
#include <hip/hip_runtime.h>

typedef short bf16x8 __attribute__((ext_vector_type(8)));
typedef float f32x4 __attribute__((ext_vector_type(4)));
typedef unsigned short us;

#define BN_EPS 1e-3f

// fp32 -> bf16 round-to-nearest-even (no NaN inputs in this net)
static __device__ __forceinline__ us f2bs(float x) {
  unsigned int u = __builtin_bit_cast(unsigned int, x);
  unsigned int r = (u + 0x7FFFu + ((u >> 16) & 1u)) >> 16;
  return (us)r;
}

// async global->LDS, 16B per lane; LDS dest is wave-uniform base + lane*16.
static __device__ __forceinline__ void gl_lds16(const us* g, us* l) {
  __builtin_amdgcn_global_load_lds(
      (const __attribute__((address_space(1))) void*)g,
      (__attribute__((address_space(3))) void*)l, 16, 0, 0);
}

// ---------------- transpose + fp32->bf16: src [K,N] f32 -> dst [N,K] bf16 ----
__global__ __launch_bounds__(256) void transpose_bf16(
    const float* __restrict__ src, us* __restrict__ dst, int K, int N,
    long sstride, long dstride) {
  long sbs = (long)blockIdx.z * sstride;
  long sbd = (long)blockIdx.z * dstride;
  __shared__ float tile[32][33];
  int tx = threadIdx.x & 31, ty = threadIdx.x >> 5;  // 32 x 8
  int k0 = blockIdx.x * 32, n0 = blockIdx.y * 32;
  for (int i = 0; i < 32; i += 8)
    tile[ty + i][tx] = src[sbs + (long)(k0 + ty + i) * N + n0 + tx];
  __syncthreads();
  for (int i = 0; i < 32; i += 8)
    dst[sbd + (long)(n0 + ty + i) * K + k0 + tx] = f2bs(tile[tx][ty + i]);
}

// ---------------- embedding: h = state @ Wemb + bemb + pes; hb = bf16(h) ----
__global__ __launch_bounds__(256) void embed_kernel(
    const float* __restrict__ state, const float* __restrict__ Wemb,
    const float* __restrict__ bemb, const float* __restrict__ pes,
    float* __restrict__ h, us* __restrict__ hb) {
  int t = threadIdx.x;
  int row0 = blockIdx.x * 8;
  __shared__ float st[8][64];
  {
    int i = t;
    st[i >> 6][i & 63] = state[(long)row0 * 64 + i];
    i += 256;
    st[i >> 6][i & 63] = state[(long)row0 * 64 + i];
  }
  __syncthreads();
  int c0 = t, c1 = t + 256;
  float acc0[8], acc1[8];
#pragma unroll
  for (int r = 0; r < 8; ++r) { acc0[r] = 0.f; acc1[r] = 0.f; }
  for (int kk = 0; kk < 64; ++kk) {
    float w0 = Wemb[kk * 512 + c0], w1 = Wemb[kk * 512 + c1];
#pragma unroll
    for (int r = 0; r < 8; ++r) {
      acc0[r] += st[r][kk] * w0;
      acc1[r] += st[r][kk] * w1;
    }
  }
  float be0 = bemb[c0], be1 = bemb[c1];
#pragma unroll
  for (int r = 0; r < 8; ++r) {
    int row = row0 + r, s = row & 255;
    float v0 = acc0[r] + be0 + pes[(long)s * 512 + c0];
    float v1 = acc1[r] + be1 + pes[(long)s * 512 + c1];
    h[(long)row * 512 + c0] = v0;
    h[(long)row * 512 + c1] = v1;
    hb[(long)row * 512 + c0] = f2bs(v0);
    hb[(long)row * 512 + c1] = f2bs(v1);
  }
}

// ---------------- generic bf16 MFMA GEMM, B given transposed [N,K] ----------
// Staging: global_load_lds width=16, linear LDS [BM][64] (BK=64), 2-barrier
// K-loop (m97 structure).
enum { EPI_QKV = 0, EPI_RESID_F32 = 1, EPI_RELU_BF16 = 2, EPI_FFN2_F32 = 3,
       EPI_FEAT = 4 };

template <int BM, int BN, int WM, int WN, int EPI>
__global__ __launch_bounds__((BM / WM) * (BN / WN) * 64)
void gemm_bt(const us* __restrict__ A, int lda, long batchA,
             const us* __restrict__ Bt, int ldb, long batchB,
             void* __restrict__ Cout, void* __restrict__ C2,
             void* __restrict__ C3, int ldc,
             const float* __restrict__ bias,
             const float* __restrict__ resid,
             const float* __restrict__ gsum, const float* __restrict__ gsumsq,
             const float* __restrict__ gamma, const float* __restrict__ beta,
             int K) {
  constexpr int WCols = BN / WN;
  constexpr int NT = (BM / WM) * (BN / WN) * 64;
  constexpr int NW = NT / 64;
  constexpr int MI = WM / 16, NI = WN / 16;
  constexpr int LA = BM / 8;  // 1KB wave-loads to fill A tile (8 rows each)
  constexpr int LB = BN / 8;
  const int tid = threadIdx.x;
  const int w = tid >> 6, l = tid & 63;
  const int wr = w / WCols, wc = w % WCols;
  const int lr = l & 15, lh = l >> 4;
  const int z = blockIdx.z;
  const long m0 = (long)blockIdx.x * BM;
  const long n0 = (long)blockIdx.y * BN;
  A += (long)z * batchA;
  Bt += (long)z * batchB;
  __shared__ __align__(16) us As[BM][64];
  __shared__ __align__(16) us Bs[BN][64];
  // per-lane source offsets for the async staging loads
  const int srow = l >> 3, scol = (l & 7) << 3;
  f32x4 acc[MI][NI] = {};
  for (int kt = 0; kt < K; kt += 64) {
    __syncthreads();  // previous tile's reads complete before overwrite
    for (int j = w; j < LA; j += NW) {
      int rb = j * 8;
      gl_lds16(A + (m0 + rb + srow) * lda + kt + scol, &As[rb][0]);
    }
    for (int j = w; j < LB; j += NW) {
      int rb = j * 8;
      gl_lds16(Bt + (n0 + rb + srow) * ldb + kt + scol, &Bs[rb][0]);
    }
    asm volatile("s_waitcnt vmcnt(0)" ::: "memory");
    __syncthreads();
#pragma unroll
    for (int kk = 0; kk < 64; kk += 32) {
      bf16x8 af[MI], bfr[NI];
#pragma unroll
      for (int mi = 0; mi < MI; ++mi)
        af[mi] = *(const bf16x8*)&As[wr * WM + mi * 16 + lr][kk + lh * 8];
#pragma unroll
      for (int ni = 0; ni < NI; ++ni)
        bfr[ni] = *(const bf16x8*)&Bs[wc * WN + ni * 16 + lr][kk + lh * 8];
#pragma unroll
      for (int mi = 0; mi < MI; ++mi)
#pragma unroll
        for (int ni = 0; ni < NI; ++ni)
          acc[mi][ni] = __builtin_amdgcn_mfma_f32_16x16x32_bf16(
              af[mi], bfr[ni], acc[mi][ni], 0, 0, 0);
    }
  }
#pragma unroll
  for (int mi = 0; mi < MI; ++mi) {
#pragma unroll
    for (int ni = 0; ni < NI; ++ni) {
      const int col = (int)n0 + wc * WN + ni * 16 + lr;
      float bv_ = 0.f;
      int segc = col;
      if constexpr (EPI == EPI_QKV) {
        int seg = col >> 9;
        segc = col & 511;
        bv_ = seg == 0 ? bias[segc] : (seg == 1 ? gamma[segc] : beta[segc]);
      } else if constexpr (EPI != EPI_FEAT) {
        bv_ = bias[col];
      }
      float aa = 0.f, bb2 = 0.f;
      if constexpr (EPI == EPI_FFN2_F32) {
        const float invN = 1.f / 16384.f;
        float mu = gsum[col] * invN;
        float var = gsumsq[col] * invN - mu * mu;
        aa = gamma[col] * rsqrtf(var + BN_EPS);
        bb2 = beta[col] - mu * aa;
      }
#pragma unroll
      for (int q_ = 0; q_ < 4; ++q_) {
        const long row = m0 + wr * WM + mi * 16 + lh * 4 + q_;
        float v = acc[mi][ni][q_] + bv_;
        if constexpr (EPI == EPI_QKV) {
          int seg = col >> 9;
          if (seg == 0) {
            ((us*)Cout)[row * 512 + segc] = f2bs(v);
          } else if (seg == 1) {
            ((us*)C2)[row * 512 + segc] = f2bs(v);
          } else {  // V, store transposed [b][h][dh][s]
            long o = (((row >> 8) * 8 + (segc >> 6)) * 64 + (segc & 63)) * 256 +
                     (row & 255);
            ((us*)C3)[o] = f2bs(v);
          }
        } else if constexpr (EPI == EPI_RESID_F32) {
          ((float*)Cout)[row * ldc + col] = v + resid[row * ldc + col];
        } else if constexpr (EPI == EPI_RELU_BF16) {
          ((us*)Cout)[row * ldc + col] = f2bs(fmaxf(v, 0.f));
        } else if constexpr (EPI == EPI_FEAT) {
          atomicAdd(&((float*)Cout)[row * ldc + col], v);
        } else {  // EPI_FFN2_F32: z = (y*a+b) + acc + bias
          float ybn = resid[row * ldc + col] * aa + bb2;
          ((float*)Cout)[row * ldc + col] = ybn + v;
        }
      }
    }
  }
}

// ---------------- fused attention v2: QK^T*scale + reg-softmax + PV ---------
// grid (2, B*H): each block owns one (b,h) half — 4 q-tiles of 32 rows.
// Softmax fully in registers (16-lane shfl_xor + 256B cross-wave LDS);
// no f32 score buffer => LDS ~31.5KB => 4-5 blocks/CU.
__global__ __launch_bounds__(256) void attn_kernel(
    const us* __restrict__ q, const us* __restrict__ k,
    const us* __restrict__ vt, us* __restrict__ ctx) {
  const int half = blockIdx.x;  // 0..1
  const int z = blockIdx.y;     // b*8+h
  const int b = z >> 3, hh = z & 7;
  const long qkBase = (long)b * 131072 + hh * 64;
  const int tid = threadIdx.x, w = tid >> 6, l = tid & 63;
  const int lr = l & 15, lh = l >> 4;
  __shared__ __align__(16) us Qs[32][72];
  __shared__ __align__(16) us Ks[64][72];   // K chunk, reused for V chunks
  __shared__ __align__(16) us Pb[32][264];  // normalized P (bf16)
  __shared__ float fred[32][2];             // cross-wave row max/sum exchange
  const int qr = (w >> 1) * 16, qc = (w & 1) * 32;
  const us* vb = vt + (long)z * 16384;
  const int ldr = tid >> 3, ldc = (tid & 7) << 3;

  for (int qi = 0; qi < 4; ++qi) {
    const int qb = half * 4 + qi;
    // Q tile load (safe: Qs last read before previous iteration's fred syncs)
    *(uint4*)&Qs[ldr][ldc] =
        *(const uint4*)(q + qkBase + (long)(qb * 32 + ldr) * 512 + ldc);
    f32x4 sacc[4][2] = {};
    for (int skb = 0; skb < 4; ++skb) {
      __syncthreads();  // Ks overwrite safe + Qs visible (skb==0)
      for (int i = tid; i < 512; i += 256) {
        int r = i >> 3, c = (i & 7) << 3;
        *(uint4*)&Ks[r][c] =
            *(const uint4*)(k + qkBase + (long)(skb * 64 + r) * 512 + c);
      }
      __syncthreads();
#pragma unroll
      for (int kh = 0; kh < 2; ++kh) {
        bf16x8 aq = *(const bf16x8*)&Qs[qr + lr][kh * 32 + lh * 8];
#pragma unroll
        for (int ni = 0; ni < 2; ++ni) {
          bf16x8 bkk = *(const bf16x8*)&Ks[qc + ni * 16 + lr][kh * 32 + lh * 8];
          sacc[skb][ni] = __builtin_amdgcn_mfma_f32_16x16x32_bf16(
              aq, bkk, sacc[skb][ni], 0, 0, 0);
        }
      }
    }
    // ---- softmax in registers ----
    // lane holds rows (qr+lh*4+q_), cols (skb*64+qc+ni*16+lr)
    float m0[4] = {-1e30f, -1e30f, -1e30f, -1e30f};
#pragma unroll
    for (int skb = 0; skb < 4; ++skb)
#pragma unroll
      for (int ni = 0; ni < 2; ++ni)
#pragma unroll
        for (int q_ = 0; q_ < 4; ++q_) {
          float v = sacc[skb][ni][q_] * 0.125f;
          sacc[skb][ni][q_] = v;
          m0[q_] = fmaxf(m0[q_], v);
        }
#pragma unroll
    for (int off = 1; off < 16; off <<= 1)
#pragma unroll
      for (int q_ = 0; q_ < 4; ++q_)
        m0[q_] = fmaxf(m0[q_], __shfl_xor(m0[q_], off));
    if (lr == 0) {
#pragma unroll
      for (int q_ = 0; q_ < 4; ++q_) fred[qr + lh * 4 + q_][w & 1] = m0[q_];
    }
    __syncthreads();
#pragma unroll
    for (int q_ = 0; q_ < 4; ++q_) {
      int row = qr + lh * 4 + q_;
      m0[q_] = fmaxf(fred[row][0], fred[row][1]);
    }
    float s0[4] = {0.f, 0.f, 0.f, 0.f};
#pragma unroll
    for (int skb = 0; skb < 4; ++skb)
#pragma unroll
      for (int ni = 0; ni < 2; ++ni)
#pragma unroll
        for (int q_ = 0; q_ < 4; ++q_) {
          float e = __expf(sacc[skb][ni][q_] - m0[q_]);
          sacc[skb][ni][q_] = e;
          s0[q_] += e;
        }
#pragma unroll
    for (int off = 1; off < 16; off <<= 1)
#pragma unroll
      for (int q_ = 0; q_ < 4; ++q_) s0[q_] += __shfl_xor(s0[q_], off);
    __syncthreads();  // max-reads of fred done before sum overwrite
    if (lr == 0) {
#pragma unroll
      for (int q_ = 0; q_ < 4; ++q_) fred[qr + lh * 4 + q_][w & 1] = s0[q_];
    }
    __syncthreads();
#pragma unroll
    for (int q_ = 0; q_ < 4; ++q_) {
      int row = qr + lh * 4 + q_;
      s0[q_] = 1.f / (fred[row][0] + fred[row][1]);
    }
    // normalized P -> LDS bf16 (MFMA A-fragment transpose)
#pragma unroll
    for (int skb = 0; skb < 4; ++skb)
#pragma unroll
      for (int ni = 0; ni < 2; ++ni)
#pragma unroll
        for (int q_ = 0; q_ < 4; ++q_)
          Pb[qr + lh * 4 + q_][skb * 64 + qc + ni * 16 + lr] =
              f2bs(sacc[skb][ni][q_] * s0[q_]);
    // ---- PV: C[32 q][64 d] = P[32][256] x V[256][64] via V^T tiles ----
    f32x4 pacc[2] = {};
    for (int kc = 0; kc < 256; kc += 64) {
      __syncthreads();  // Pb visible (kc==0); prior Ks reads done
      for (int i = tid; i < 512; i += 256) {
        int r = i >> 3, c = (i & 7) << 3;
        *(uint4*)&Ks[r][c] = *(const uint4*)(vb + (long)r * 256 + kc + c);
      }
      __syncthreads();
#pragma unroll
      for (int kh = 0; kh < 2; ++kh) {
        bf16x8 ap = *(const bf16x8*)&Pb[qr + lr][kc + kh * 32 + lh * 8];
#pragma unroll
        for (int ni = 0; ni < 2; ++ni) {
          bf16x8 bv2 = *(const bf16x8*)&Ks[qc + ni * 16 + lr][kh * 32 + lh * 8];
          pacc[ni] = __builtin_amdgcn_mfma_f32_16x16x32_bf16(
              ap, bv2, pacc[ni], 0, 0, 0);
        }
      }
    }
    const long cb2 = ((long)(b * 256 + qb * 32)) * 512 + hh * 64;
#pragma unroll
    for (int ni = 0; ni < 2; ++ni)
#pragma unroll
      for (int q_ = 0; q_ < 4; ++q_) {
        int row = qr + lh * 4 + q_;
        int col = qc + ni * 16 + lr;
        ctx[cb2 + (long)row * 512 + col] = f2bs(pacc[ni][q_]);
      }
  }
}

// ---------------- BN stats / apply ------------------------------------------
__global__ __launch_bounds__(256) void bn_stats(const float* __restrict__ y,
                                                float* __restrict__ gsum,
                                                float* __restrict__ gsumsq) {
  int t = threadIdx.x;
  long base = (long)blockIdx.x * 64 * 512;
  float s0 = 0, q0 = 0, s1 = 0, q1 = 0;
  for (int r = 0; r < 64; ++r) {
    float v0 = y[base + r * 512 + t];
    float v1 = y[base + r * 512 + t + 256];
    s0 += v0; q0 += v0 * v0;
    s1 += v1; q1 += v1 * v1;
  }
  atomicAdd(&gsum[t], s0);
  atomicAdd(&gsumsq[t], q0);
  atomicAdd(&gsum[t + 256], s1);
  atomicAdd(&gsumsq[t + 256], q1);
}

__global__ __launch_bounds__(256) void bn_apply(
    const float* __restrict__ y, const float* __restrict__ gsum,
    const float* __restrict__ gsumsq, const float* __restrict__ gamma,
    const float* __restrict__ beta, us* __restrict__ ybb) {
  long i4 = (long)blockIdx.x * 256 + threadIdx.x;
  long e = i4 * 4;
  int c = (int)(e & 511);
  const float invN = 1.f / 16384.f;
  float4 v = *(const float4*)(y + e);
  float vv[4] = {v.x, v.y, v.z, v.w};
  ushort4 r;
  us* rp = (us*)&r;
#pragma unroll
  for (int j = 0; j < 4; ++j) {
    int cj = c + j;
    float mu = gsum[cj] * invN;
    float var = gsumsq[cj] * invN - mu * mu;
    float a = gamma[cj] * rsqrtf(var + BN_EPS);
    float b = beta[cj] - mu * a;
    rp[j] = f2bs(vv[j] * a + b);
  }
  *(ushort4*)(ybb + e) = r;
}

// ---------------- LayerNorm per row -> h (f32) + hb (bf16) ------------------
__global__ __launch_bounds__(128) void ln_kernel(
    const float* __restrict__ zin, const float* __restrict__ g,
    const float* __restrict__ b, float* __restrict__ hout,
    us* __restrict__ hb) {
  int r = blockIdx.x, t = threadIdx.x;
  const float* zr = zin + (long)r * 512;
  float4 v = *(const float4*)(zr + t * 4);
  float s = v.x + v.y + v.z + v.w;
  float qs = v.x * v.x + v.y * v.y + v.z * v.z + v.w * v.w;
  for (int off = 32; off >= 1; off >>= 1) {
    s += __shfl_down(s, off);
    qs += __shfl_down(qs, off);
  }
  __shared__ float ls[2], lq[2];
  if ((t & 63) == 0) {
    ls[t >> 6] = s;
    lq[t >> 6] = qs;
  }
  __syncthreads();
  float mu = (ls[0] + ls[1]) * (1.f / 512.f);
  float var = (lq[0] + lq[1]) * (1.f / 512.f) - mu * mu;
  float rs = rsqrtf(var + BN_EPS);
  float4 gg = *(const float4*)(g + t * 4);
  float4 bb = *(const float4*)(b + t * 4);
  float o0 = gg.x * (v.x - mu) * rs + bb.x;
  float o1 = gg.y * (v.y - mu) * rs + bb.y;
  float o2 = gg.z * (v.z - mu) * rs + bb.z;
  float o3 = gg.w * (v.w - mu) * rs + bb.w;
  *(float4*)(hout + (long)r * 512 + t * 4) = make_float4(o0, o1, o2, o3);
  ushort4 hv;
  us* hp = (us*)&hv;
  hp[0] = f2bs(o0); hp[1] = f2bs(o1); hp[2] = f2bs(o2); hp[3] = f2bs(o3);
  *(ushort4*)(hb + (long)r * 512 + t * 4) = hv;
}

// ---------------- head ------------------------------------------------------
__global__ void zerof(float* __restrict__ p, int n) {
  int i = blockIdx.x * 256 + threadIdx.x;
  if (i < n) p[i] = 0.f;
}

__global__ __launch_bounds__(320) void final_head(
    const float* __restrict__ feat, const float* __restrict__ bf_,
    const float* __restrict__ action, const float* __restrict__ Wfin,
    const float* __restrict__ bfin, float* __restrict__ out) {
  int t = threadIdx.x;
  int b = t & 63, o = t >> 6;  // 64 x 5
  float acc = bfin[o];
  for (int j = 0; j < 32; ++j) acc += (feat[b * 32 + j] + bf_[j]) * Wfin[j * 5 + o];
  for (int j = 0; j < 8; ++j) acc += action[b * 8 + j] * Wfin[(32 + j) * 5 + o];
  out[b * 5 + o] = acc;
}

// ---------------- host ------------------------------------------------------
extern "C" void kernel_launch(void* const* d_in, const int* in_sizes, int n_in,
                              void* d_out, int out_size, void* d_ws,
                              size_t ws_size, hipStream_t stream) {
  const float* state = (const float*)d_in[0];
  const float* action = (const float*)d_in[1];
  const float* pes = (const float*)d_in[2];
  const float* W_emb = (const float*)d_in[3];
  const float* b_emb = (const float*)d_in[4];
  const float* Wq = (const float*)d_in[5];
  const float* bq = (const float*)d_in[6];
  const float* Wk = (const float*)d_in[7];
  const float* bk = (const float*)d_in[8];
  const float* Wv = (const float*)d_in[9];
  const float* bv = (const float*)d_in[10];
  const float* Wo = (const float*)d_in[11];
  const float* bo = (const float*)d_in[12];
  const float* bn_g = (const float*)d_in[13];
  const float* bn_b = (const float*)d_in[14];
  const float* W1 = (const float*)d_in[15];
  const float* b1 = (const float*)d_in[16];
  const float* W2 = (const float*)d_in[17];
  const float* b2 = (const float*)d_in[18];
  const float* ln_g = (const float*)d_in[19];
  const float* ln_b = (const float*)d_in[20];
  const float* Wf = (const float*)d_in[21];
  const float* bf_ = (const float*)d_in[22];
  const float* Wfin = (const float*)d_in[23];
  const float* bfin = (const float*)d_in[24];
  float* out = (float*)d_out;
  (void)in_sizes; (void)n_in; (void)out_size;

  char* wp = (char*)d_ws;
  size_t off = 0;
  auto take = [&](size_t bytes) {
    void* p = wp + off;
    off += (bytes + 255) & ~(size_t)255;
    return p;
  };
  // Persistent across the whole launch:
  us* qkvT = (us*)take(6ull * 1536 * 512 * 2);  // [l][{q,k,v}*512][512]
  us* WoT = (us*)take(6ull * 512 * 512 * 2);
  us* W1T = (us*)take(6ull * 2048 * 512 * 2);
  us* W2T = (us*)take(6ull * 512 * 2048 * 2);
  us* WfT = (us*)take(32ull * 131072 * 2);      // [32][131072]
  float* h = (float*)take(16384ull * 512 * 4);   // f32 activations (resid)
  us* hb = (us*)take(16384ull * 512 * 2);        // bf16 copy of h
  float* y = (float*)take(16384ull * 512 * 4);   // attn-block output (pre-BN)
  // Aliased regions (lifetime analysis; all transitions write-after-last-read
  // on the same stream):
  //   R1: q -> z[0:8M)     R2: k -> y_bn(bf16) -> z[8M:16M)
  //   R3: vT               R4: ctx -> ffn hidden f1
  us* qb_ = (us*)take(16384ull * 512 * 2);       // R1
  us* kb_ = (us*)take(16384ull * 512 * 2);       // R2 (contiguous after R1)
  us* vt = (us*)take(16384ull * 512 * 2);        // R3
  us* bigR4 = (us*)take(33554432ull * 2);        // R4
  float* gsum = (float*)take(512 * 4);
  float* gsumsq = (float*)take(512 * 4);
  float* feat = (float*)take(2048 * 4);
  us* ctxb = bigR4;        // R4 (ctx live attn -> Wo; must NOT alias q/k/vt:
                           //     fused attn reads q,k,vt while writing ctx)
  us* f1 = bigR4;          // R4 reuse (ctx dead after Wo; f1 written by FFN1)
  us* ybb = kb_;           // alias R2 (k dead after attn_kernel)
  float* zb = (float*)qb_; // alias R1+R2 (q dead after attn, ybb dead after FFN1)

  // Workspace guard: clean diagnostic failure instead of GPU fault if pool
  // is smaller than planned.
  if (off > ws_size) return;

  transpose_bf16<<<dim3(16, 16, 6), 256, 0, stream>>>(Wq, qkvT, 512, 512,
                                                      262144, 786432);
  transpose_bf16<<<dim3(16, 16, 6), 256, 0, stream>>>(Wk, qkvT + 262144, 512,
                                                      512, 262144, 786432);
  transpose_bf16<<<dim3(16, 16, 6), 256, 0, stream>>>(Wv, qkvT + 524288, 512,
                                                      512, 262144, 786432);
  transpose_bf16<<<dim3(16, 16, 6), 256, 0, stream>>>(Wo, WoT, 512, 512,
                                                      262144, 262144);
  transpose_bf16<<<dim3(16, 64, 6), 256, 0, stream>>>(W1, W1T, 512, 2048,
                                                      1048576, 1048576);
  transpose_bf16<<<dim3(64, 16, 6), 256, 0, stream>>>(W2, W2T, 2048, 512,
                                                      1048576, 1048576);
  transpose_bf16<<<dim3(4096, 1, 1), 256, 0, stream>>>(Wf, WfT, 131072, 32,
                                                       0, 0);
  embed_kernel<<<2048, 256, 0, stream>>>(state, W_emb, b_emb, pes, h, hb);

  for (int l = 0; l < 6; ++l) {
    const us* qkvTl = qkvT + (size_t)l * 786432;
    const us* WoTl = WoT + (size_t)l * 262144;
    const us* W1Tl = W1T + (size_t)l * 1048576;
    const us* W2Tl = W2T + (size_t)l * 1048576;

    // fused QKV: N=1536, writes q, k, and v-transposed in one pass
    gemm_bt<128, 128, 64, 64, EPI_QKV><<<dim3(128, 12, 1), 256, 0, stream>>>(
        hb, 512, 0, qkvTl, 512, 0, qb_, kb_, vt, 512, bq + l * 512,
        nullptr, nullptr, nullptr, bk + l * 512, bv + l * 512, 512);
    // fused attention v2: QK^T + reg-softmax + PV -> ctx
    attn_kernel<<<dim3(2, 512), 256, 0, stream>>>(qb_, kb_, vt, ctxb);
    gemm_bt<64, 128, 32, 64, EPI_RESID_F32><<<dim3(256, 4, 1), 256, 0, stream>>>(
        ctxb, 512, 0, WoTl, 512, 0, y, nullptr, nullptr, 512, bo + l * 512,
        h, nullptr, nullptr, nullptr, nullptr, 512);
    zerof<<<4, 256, 0, stream>>>(gsum, 1024);  // gsum+gsumsq contiguous
    bn_stats<<<256, 256, 0, stream>>>(y, gsum, gsumsq);
    bn_apply<<<8192, 256, 0, stream>>>(y, gsum, gsumsq, bn_g + l * 512,
                                       bn_b + l * 512, ybb);
    gemm_bt<128, 128, 64, 64, EPI_RELU_BF16><<<dim3(128, 16, 1), 256, 0, stream>>>(
        ybb, 512, 0, W1Tl, 512, 0, f1, nullptr, nullptr, 2048, b1 + l * 2048,
        nullptr, nullptr, nullptr, nullptr, nullptr, 512);
    gemm_bt<64, 128, 32, 64, EPI_FFN2_F32><<<dim3(256, 4, 1), 256, 0, stream>>>(
        f1, 2048, 0, W2Tl, 2048, 0, zb, nullptr, nullptr, 512, b2 + l * 512,
        y, gsum, gsumsq, bn_g + l * 512, bn_b + l * 512, 2048);
    ln_kernel<<<16384, 128, 0, stream>>>(zb, ln_g + l * 512, ln_b + l * 512, h, hb);
  }

  // feat = flat @ Wf: plain GEMM M=64,N=32,K=131072 (flat rows are contiguous
  // hb slices), split-K over 128 chunks of 1024, fp32 atomic accumulate.
  zerof<<<8, 256, 0, stream>>>(feat, 2048);
  gemm_bt<64, 32, 32, 16, EPI_FEAT><<<dim3(1, 1, 128), 256, 0, stream>>>(
      hb, 131072, 1024, WfT, 131072, 1024, feat, nullptr, nullptr, 32,
      nullptr, nullptr, nullptr, nullptr, nullptr, nullptr, 1024);
  final_head<<<1, 320, 0, stream>>>(feat, bf_, action, Wfin, bfin, out);
}

// Round 7
// 1762.375 us; speedup vs baseline: 1.1492x; 1.0624x over previous
//
#include <hip/hip_runtime.h>

typedef short bf16x8 __attribute__((ext_vector_type(8)));
typedef float f32x4 __attribute__((ext_vector_type(4)));
typedef unsigned short us;

#define BN_EPS 1e-3f

// fp32 -> bf16 round-to-nearest-even (no NaN inputs in this net)
static __device__ __forceinline__ us f2bs(float x) {
  unsigned int u = __builtin_bit_cast(unsigned int, x);
  unsigned int r = (u + 0x7FFFu + ((u >> 16) & 1u)) >> 16;
  return (us)r;
}

// async global->LDS, 16B per lane; LDS dest is wave-uniform base + lane*16.
static __device__ __forceinline__ void gl_lds16(const us* g, us* l) {
  __builtin_amdgcn_global_load_lds(
      (const __attribute__((address_space(1))) void*)g,
      (__attribute__((address_space(3))) void*)l, 16, 0, 0);
}

// ---------------- transpose + fp32->bf16: src [K,N] f32 -> dst [N,K] bf16 ----
__global__ __launch_bounds__(256) void transpose_bf16(
    const float* __restrict__ src, us* __restrict__ dst, int K, int N,
    long sstride, long dstride) {
  long sbs = (long)blockIdx.z * sstride;
  long sbd = (long)blockIdx.z * dstride;
  __shared__ float tile[32][33];
  int tx = threadIdx.x & 31, ty = threadIdx.x >> 5;  // 32 x 8
  int k0 = blockIdx.x * 32, n0 = blockIdx.y * 32;
  for (int i = 0; i < 32; i += 8)
    tile[ty + i][tx] = src[sbs + (long)(k0 + ty + i) * N + n0 + tx];
  __syncthreads();
  for (int i = 0; i < 32; i += 8)
    dst[sbd + (long)(n0 + ty + i) * K + k0 + tx] = f2bs(tile[tx][ty + i]);
}

// ---------------- embedding: h = state @ Wemb + bemb + pes; hb = bf16(h) ----
__global__ __launch_bounds__(256) void embed_kernel(
    const float* __restrict__ state, const float* __restrict__ Wemb,
    const float* __restrict__ bemb, const float* __restrict__ pes,
    float* __restrict__ h, us* __restrict__ hb) {
  int t = threadIdx.x;
  int row0 = blockIdx.x * 8;
  __shared__ float st[8][64];
  {
    int i = t;
    st[i >> 6][i & 63] = state[(long)row0 * 64 + i];
    i += 256;
    st[i >> 6][i & 63] = state[(long)row0 * 64 + i];
  }
  __syncthreads();
  int c0 = t, c1 = t + 256;
  float acc0[8], acc1[8];
#pragma unroll
  for (int r = 0; r < 8; ++r) { acc0[r] = 0.f; acc1[r] = 0.f; }
  for (int kk = 0; kk < 64; ++kk) {
    float w0 = Wemb[kk * 512 + c0], w1 = Wemb[kk * 512 + c1];
#pragma unroll
    for (int r = 0; r < 8; ++r) {
      acc0[r] += st[r][kk] * w0;
      acc1[r] += st[r][kk] * w1;
    }
  }
  float be0 = bemb[c0], be1 = bemb[c1];
#pragma unroll
  for (int r = 0; r < 8; ++r) {
    int row = row0 + r, s = row & 255;
    float v0 = acc0[r] + be0 + pes[(long)s * 512 + c0];
    float v1 = acc1[r] + be1 + pes[(long)s * 512 + c1];
    h[(long)row * 512 + c0] = v0;
    h[(long)row * 512 + c1] = v1;
    hb[(long)row * 512 + c0] = f2bs(v0);
    hb[(long)row * 512 + c1] = f2bs(v1);
  }
}

// ---------------- generic bf16 MFMA GEMM, B given transposed [N,K] ----------
// Staging: global_load_lds width=16, linear LDS [BM][64] (BK=64), 2-barrier
// K-loop (m97 structure). NOTE: 128x128 tile is the verified sweet spot for
// this structure (R6 lesson: 64x128 regressed FFN2 67->105us).
enum { EPI_QKV = 0, EPI_RESID_F32 = 1, EPI_RELU_BF16 = 2, EPI_FFN2_F32 = 3,
       EPI_FEAT = 4 };

template <int BM, int BN, int WM, int WN, int EPI>
__global__ __launch_bounds__((BM / WM) * (BN / WN) * 64)
void gemm_bt(const us* __restrict__ A, int lda, long batchA,
             const us* __restrict__ Bt, int ldb, long batchB,
             void* __restrict__ Cout, void* __restrict__ C2,
             void* __restrict__ C3, int ldc,
             const float* __restrict__ bias,
             const float* __restrict__ resid,
             const float* __restrict__ gsum, const float* __restrict__ gsumsq,
             const float* __restrict__ gamma, const float* __restrict__ beta,
             int K) {
  constexpr int WCols = BN / WN;
  constexpr int NT = (BM / WM) * (BN / WN) * 64;
  constexpr int NW = NT / 64;
  constexpr int MI = WM / 16, NI = WN / 16;
  constexpr int LA = BM / 8;  // 1KB wave-loads to fill A tile (8 rows each)
  constexpr int LB = BN / 8;
  const int tid = threadIdx.x;
  const int w = tid >> 6, l = tid & 63;
  const int wr = w / WCols, wc = w % WCols;
  const int lr = l & 15, lh = l >> 4;
  const int z = blockIdx.z;
  const long m0 = (long)blockIdx.x * BM;
  const long n0 = (long)blockIdx.y * BN;
  A += (long)z * batchA;
  Bt += (long)z * batchB;
  __shared__ __align__(16) us As[BM][64];
  __shared__ __align__(16) us Bs[BN][64];
  // per-lane source offsets for the async staging loads
  const int srow = l >> 3, scol = (l & 7) << 3;
  f32x4 acc[MI][NI] = {};
  for (int kt = 0; kt < K; kt += 64) {
    __syncthreads();  // previous tile's reads complete before overwrite
    for (int j = w; j < LA; j += NW) {
      int rb = j * 8;
      gl_lds16(A + (m0 + rb + srow) * lda + kt + scol, &As[rb][0]);
    }
    for (int j = w; j < LB; j += NW) {
      int rb = j * 8;
      gl_lds16(Bt + (n0 + rb + srow) * ldb + kt + scol, &Bs[rb][0]);
    }
    asm volatile("s_waitcnt vmcnt(0)" ::: "memory");
    __syncthreads();
#pragma unroll
    for (int kk = 0; kk < 64; kk += 32) {
      bf16x8 af[MI], bfr[NI];
#pragma unroll
      for (int mi = 0; mi < MI; ++mi)
        af[mi] = *(const bf16x8*)&As[wr * WM + mi * 16 + lr][kk + lh * 8];
#pragma unroll
      for (int ni = 0; ni < NI; ++ni)
        bfr[ni] = *(const bf16x8*)&Bs[wc * WN + ni * 16 + lr][kk + lh * 8];
#pragma unroll
      for (int mi = 0; mi < MI; ++mi)
#pragma unroll
        for (int ni = 0; ni < NI; ++ni)
          acc[mi][ni] = __builtin_amdgcn_mfma_f32_16x16x32_bf16(
              af[mi], bfr[ni], acc[mi][ni], 0, 0, 0);
    }
  }
#pragma unroll
  for (int mi = 0; mi < MI; ++mi) {
#pragma unroll
    for (int ni = 0; ni < NI; ++ni) {
      const int col = (int)n0 + wc * WN + ni * 16 + lr;
      float bv_ = 0.f;
      int segc = col;
      if constexpr (EPI == EPI_QKV) {
        int seg = col >> 9;
        segc = col & 511;
        bv_ = seg == 0 ? bias[segc] : (seg == 1 ? gamma[segc] : beta[segc]);
      } else if constexpr (EPI != EPI_FEAT) {
        bv_ = bias[col];
      }
      float aa = 0.f, bb2 = 0.f;
      if constexpr (EPI == EPI_FFN2_F32) {
        const float invN = 1.f / 16384.f;
        float mu = gsum[col] * invN;
        float var = gsumsq[col] * invN - mu * mu;
        aa = gamma[col] * rsqrtf(var + BN_EPS);
        bb2 = beta[col] - mu * aa;
      }
#pragma unroll
      for (int q_ = 0; q_ < 4; ++q_) {
        const long row = m0 + wr * WM + mi * 16 + lh * 4 + q_;
        float v = acc[mi][ni][q_] + bv_;
        if constexpr (EPI == EPI_QKV) {
          int seg = col >> 9;
          if (seg == 0) {
            ((us*)Cout)[row * 512 + segc] = f2bs(v);
          } else if (seg == 1) {
            ((us*)C2)[row * 512 + segc] = f2bs(v);
          } else {  // V, store transposed [b][h][dh][s]
            long o = (((row >> 8) * 8 + (segc >> 6)) * 64 + (segc & 63)) * 256 +
                     (row & 255);
            ((us*)C3)[o] = f2bs(v);
          }
        } else if constexpr (EPI == EPI_RESID_F32) {
          ((float*)Cout)[row * ldc + col] = v + resid[row * ldc + col];
        } else if constexpr (EPI == EPI_RELU_BF16) {
          ((us*)Cout)[row * ldc + col] = f2bs(fmaxf(v, 0.f));
        } else if constexpr (EPI == EPI_FEAT) {
          atomicAdd(&((float*)Cout)[row * ldc + col], v);
        } else {  // EPI_FFN2_F32: z = (y*a+b) + acc + bias
          float ybn = resid[row * ldc + col] * aa + bb2;
          ((float*)Cout)[row * ldc + col] = ybn + v;
        }
      }
    }
  }
}

// ---------------- fused attention v2: QK^T*scale + reg-softmax + PV ---------
// grid (2, B*H): each block owns one (b,h) half — 4 q-tiles of 32 rows.
// Softmax fully in registers (16-lane shfl_xor + 256B cross-wave LDS);
// no f32 score buffer => LDS ~31.5KB => 4-5 blocks/CU.
__global__ __launch_bounds__(256) void attn_kernel(
    const us* __restrict__ q, const us* __restrict__ k,
    const us* __restrict__ vt, us* __restrict__ ctx) {
  const int half = blockIdx.x;  // 0..1
  const int z = blockIdx.y;     // b*8+h
  const int b = z >> 3, hh = z & 7;
  const long qkBase = (long)b * 131072 + hh * 64;
  const int tid = threadIdx.x, w = tid >> 6, l = tid & 63;
  const int lr = l & 15, lh = l >> 4;
  __shared__ __align__(16) us Qs[32][72];
  __shared__ __align__(16) us Ks[64][72];   // K chunk, reused for V chunks
  __shared__ __align__(16) us Pb[32][264];  // normalized P (bf16)
  __shared__ float fred[32][2];             // cross-wave row max/sum exchange
  const int qr = (w >> 1) * 16, qc = (w & 1) * 32;
  const us* vb = vt + (long)z * 16384;
  const int ldr = tid >> 3, ldc = (tid & 7) << 3;

  for (int qi = 0; qi < 4; ++qi) {
    const int qb = half * 4 + qi;
    // Q tile load (safe: Qs last read before previous iteration's fred syncs)
    *(uint4*)&Qs[ldr][ldc] =
        *(const uint4*)(q + qkBase + (long)(qb * 32 + ldr) * 512 + ldc);
    f32x4 sacc[4][2] = {};
    for (int skb = 0; skb < 4; ++skb) {
      __syncthreads();  // Ks overwrite safe + Qs visible (skb==0)
      for (int i = tid; i < 512; i += 256) {
        int r = i >> 3, c = (i & 7) << 3;
        *(uint4*)&Ks[r][c] =
            *(const uint4*)(k + qkBase + (long)(skb * 64 + r) * 512 + c);
      }
      __syncthreads();
#pragma unroll
      for (int kh = 0; kh < 2; ++kh) {
        bf16x8 aq = *(const bf16x8*)&Qs[qr + lr][kh * 32 + lh * 8];
#pragma unroll
        for (int ni = 0; ni < 2; ++ni) {
          bf16x8 bkk = *(const bf16x8*)&Ks[qc + ni * 16 + lr][kh * 32 + lh * 8];
          sacc[skb][ni] = __builtin_amdgcn_mfma_f32_16x16x32_bf16(
              aq, bkk, sacc[skb][ni], 0, 0, 0);
        }
      }
    }
    // ---- softmax in registers ----
    float m0[4] = {-1e30f, -1e30f, -1e30f, -1e30f};
#pragma unroll
    for (int skb = 0; skb < 4; ++skb)
#pragma unroll
      for (int ni = 0; ni < 2; ++ni)
#pragma unroll
        for (int q_ = 0; q_ < 4; ++q_) {
          float v = sacc[skb][ni][q_] * 0.125f;
          sacc[skb][ni][q_] = v;
          m0[q_] = fmaxf(m0[q_], v);
        }
#pragma unroll
    for (int off = 1; off < 16; off <<= 1)
#pragma unroll
      for (int q_ = 0; q_ < 4; ++q_)
        m0[q_] = fmaxf(m0[q_], __shfl_xor(m0[q_], off));
    if (lr == 0) {
#pragma unroll
      for (int q_ = 0; q_ < 4; ++q_) fred[qr + lh * 4 + q_][w & 1] = m0[q_];
    }
    __syncthreads();
#pragma unroll
    for (int q_ = 0; q_ < 4; ++q_) {
      int row = qr + lh * 4 + q_;
      m0[q_] = fmaxf(fred[row][0], fred[row][1]);
    }
    float s0[4] = {0.f, 0.f, 0.f, 0.f};
#pragma unroll
    for (int skb = 0; skb < 4; ++skb)
#pragma unroll
      for (int ni = 0; ni < 2; ++ni)
#pragma unroll
        for (int q_ = 0; q_ < 4; ++q_) {
          float e = __expf(sacc[skb][ni][q_] - m0[q_]);
          sacc[skb][ni][q_] = e;
          s0[q_] += e;
        }
#pragma unroll
    for (int off = 1; off < 16; off <<= 1)
#pragma unroll
      for (int q_ = 0; q_ < 4; ++q_) s0[q_] += __shfl_xor(s0[q_], off);
    __syncthreads();  // max-reads of fred done before sum overwrite
    if (lr == 0) {
#pragma unroll
      for (int q_ = 0; q_ < 4; ++q_) fred[qr + lh * 4 + q_][w & 1] = s0[q_];
    }
    __syncthreads();
#pragma unroll
    for (int q_ = 0; q_ < 4; ++q_) {
      int row = qr + lh * 4 + q_;
      s0[q_] = 1.f / (fred[row][0] + fred[row][1]);
    }
    // normalized P -> LDS bf16 (MFMA A-fragment transpose)
#pragma unroll
    for (int skb = 0; skb < 4; ++skb)
#pragma unroll
      for (int ni = 0; ni < 2; ++ni)
#pragma unroll
        for (int q_ = 0; q_ < 4; ++q_)
          Pb[qr + lh * 4 + q_][skb * 64 + qc + ni * 16 + lr] =
              f2bs(sacc[skb][ni][q_] * s0[q_]);
    // ---- PV: C[32 q][64 d] = P[32][256] x V[256][64] via V^T tiles ----
    f32x4 pacc[2] = {};
    for (int kc = 0; kc < 256; kc += 64) {
      __syncthreads();  // Pb visible (kc==0); prior Ks reads done
      for (int i = tid; i < 512; i += 256) {
        int r = i >> 3, c = (i & 7) << 3;
        *(uint4*)&Ks[r][c] = *(const uint4*)(vb + (long)r * 256 + kc + c);
      }
      __syncthreads();
#pragma unroll
      for (int kh = 0; kh < 2; ++kh) {
        bf16x8 ap = *(const bf16x8*)&Pb[qr + lr][kc + kh * 32 + lh * 8];
#pragma unroll
        for (int ni = 0; ni < 2; ++ni) {
          bf16x8 bv2 = *(const bf16x8*)&Ks[qc + ni * 16 + lr][kh * 32 + lh * 8];
          pacc[ni] = __builtin_amdgcn_mfma_f32_16x16x32_bf16(
              ap, bv2, pacc[ni], 0, 0, 0);
        }
      }
    }
    const long cb2 = ((long)(b * 256 + qb * 32)) * 512 + hh * 64;
#pragma unroll
    for (int ni = 0; ni < 2; ++ni)
#pragma unroll
      for (int q_ = 0; q_ < 4; ++q_) {
        int row = qr + lh * 4 + q_;
        int col = qc + ni * 16 + lr;
        ctx[cb2 + (long)row * 512 + col] = f2bs(pacc[ni][q_]);
      }
  }
}

// ---------------- BN stats / apply ------------------------------------------
__global__ __launch_bounds__(256) void bn_stats(const float* __restrict__ y,
                                                float* __restrict__ gsum,
                                                float* __restrict__ gsumsq) {
  int t = threadIdx.x;
  long base = (long)blockIdx.x * 64 * 512;
  float s0 = 0, q0 = 0, s1 = 0, q1 = 0;
  for (int r = 0; r < 64; ++r) {
    float v0 = y[base + r * 512 + t];
    float v1 = y[base + r * 512 + t + 256];
    s0 += v0; q0 += v0 * v0;
    s1 += v1; q1 += v1 * v1;
  }
  atomicAdd(&gsum[t], s0);
  atomicAdd(&gsumsq[t], q0);
  atomicAdd(&gsum[t + 256], s1);
  atomicAdd(&gsumsq[t + 256], q1);
}

__global__ __launch_bounds__(256) void bn_apply(
    const float* __restrict__ y, const float* __restrict__ gsum,
    const float* __restrict__ gsumsq, const float* __restrict__ gamma,
    const float* __restrict__ beta, us* __restrict__ ybb) {
  long i4 = (long)blockIdx.x * 256 + threadIdx.x;
  long e = i4 * 4;
  int c = (int)(e & 511);
  const float invN = 1.f / 16384.f;
  float4 v = *(const float4*)(y + e);
  float vv[4] = {v.x, v.y, v.z, v.w};
  ushort4 r;
  us* rp = (us*)&r;
#pragma unroll
  for (int j = 0; j < 4; ++j) {
    int cj = c + j;
    float mu = gsum[cj] * invN;
    float var = gsumsq[cj] * invN - mu * mu;
    float a = gamma[cj] * rsqrtf(var + BN_EPS);
    float b = beta[cj] - mu * a;
    rp[j] = f2bs(vv[j] * a + b);
  }
  *(ushort4*)(ybb + e) = r;
}

// ---------------- LayerNorm per row -> h (f32) + hb (bf16) ------------------
__global__ __launch_bounds__(128) void ln_kernel(
    const float* __restrict__ zin, const float* __restrict__ g,
    const float* __restrict__ b, float* __restrict__ hout,
    us* __restrict__ hb) {
  int r = blockIdx.x, t = threadIdx.x;
  const float* zr = zin + (long)r * 512;
  float4 v = *(const float4*)(zr + t * 4);
  float s = v.x + v.y + v.z + v.w;
  float qs = v.x * v.x + v.y * v.y + v.z * v.z + v.w * v.w;
  for (int off = 32; off >= 1; off >>= 1) {
    s += __shfl_down(s, off);
    qs += __shfl_down(qs, off);
  }
  __shared__ float ls[2], lq[2];
  if ((t & 63) == 0) {
    ls[t >> 6] = s;
    lq[t >> 6] = qs;
  }
  __syncthreads();
  float mu = (ls[0] + ls[1]) * (1.f / 512.f);
  float var = (lq[0] + lq[1]) * (1.f / 512.f) - mu * mu;
  float rs = rsqrtf(var + BN_EPS);
  float4 gg = *(const float4*)(g + t * 4);
  float4 bb = *(const float4*)(b + t * 4);
  float o0 = gg.x * (v.x - mu) * rs + bb.x;
  float o1 = gg.y * (v.y - mu) * rs + bb.y;
  float o2 = gg.z * (v.z - mu) * rs + bb.z;
  float o3 = gg.w * (v.w - mu) * rs + bb.w;
  *(float4*)(hout + (long)r * 512 + t * 4) = make_float4(o0, o1, o2, o3);
  ushort4 hv;
  us* hp = (us*)&hv;
  hp[0] = f2bs(o0); hp[1] = f2bs(o1); hp[2] = f2bs(o2); hp[3] = f2bs(o3);
  *(ushort4*)(hb + (long)r * 512 + t * 4) = hv;
}

// ---------------- head ------------------------------------------------------
__global__ void zerof(float* __restrict__ p, int n) {
  int i = blockIdx.x * 256 + threadIdx.x;
  if (i < n) p[i] = 0.f;
}

__global__ __launch_bounds__(320) void final_head(
    const float* __restrict__ feat, const float* __restrict__ bf_,
    const float* __restrict__ action, const float* __restrict__ Wfin,
    const float* __restrict__ bfin, float* __restrict__ out) {
  int t = threadIdx.x;
  int b = t & 63, o = t >> 6;  // 64 x 5
  float acc = bfin[o];
  for (int j = 0; j < 32; ++j) acc += (feat[b * 32 + j] + bf_[j]) * Wfin[j * 5 + o];
  for (int j = 0; j < 8; ++j) acc += action[b * 8 + j] * Wfin[(32 + j) * 5 + o];
  out[b * 5 + o] = acc;
}

// ---------------- host ------------------------------------------------------
extern "C" void kernel_launch(void* const* d_in, const int* in_sizes, int n_in,
                              void* d_out, int out_size, void* d_ws,
                              size_t ws_size, hipStream_t stream) {
  const float* state = (const float*)d_in[0];
  const float* action = (const float*)d_in[1];
  const float* pes = (const float*)d_in[2];
  const float* W_emb = (const float*)d_in[3];
  const float* b_emb = (const float*)d_in[4];
  const float* Wq = (const float*)d_in[5];
  const float* bq = (const float*)d_in[6];
  const float* Wk = (const float*)d_in[7];
  const float* bk = (const float*)d_in[8];
  const float* Wv = (const float*)d_in[9];
  const float* bv = (const float*)d_in[10];
  const float* Wo = (const float*)d_in[11];
  const float* bo = (const float*)d_in[12];
  const float* bn_g = (const float*)d_in[13];
  const float* bn_b = (const float*)d_in[14];
  const float* W1 = (const float*)d_in[15];
  const float* b1 = (const float*)d_in[16];
  const float* W2 = (const float*)d_in[17];
  const float* b2 = (const float*)d_in[18];
  const float* ln_g = (const float*)d_in[19];
  const float* ln_b = (const float*)d_in[20];
  const float* Wf = (const float*)d_in[21];
  const float* bf_ = (const float*)d_in[22];
  const float* Wfin = (const float*)d_in[23];
  const float* bfin = (const float*)d_in[24];
  float* out = (float*)d_out;
  (void)in_sizes; (void)n_in; (void)out_size;

  char* wp = (char*)d_ws;
  size_t off = 0;
  auto take = [&](size_t bytes) {
    void* p = wp + off;
    off += (bytes + 255) & ~(size_t)255;
    return p;
  };
  // Persistent across the whole launch:
  us* qkvT = (us*)take(6ull * 1536 * 512 * 2);  // [l][{q,k,v}*512][512]
  us* WoT = (us*)take(6ull * 512 * 512 * 2);
  us* W1T = (us*)take(6ull * 2048 * 512 * 2);
  us* W2T = (us*)take(6ull * 512 * 2048 * 2);
  us* WfT = (us*)take(32ull * 131072 * 2);      // [32][131072]
  float* h = (float*)take(16384ull * 512 * 4);   // f32 activations (resid)
  us* hb = (us*)take(16384ull * 512 * 2);        // bf16 copy of h
  float* y = (float*)take(16384ull * 512 * 4);   // attn-block output (pre-BN)
  // Aliased regions (lifetime analysis; all transitions write-after-last-read
  // on the same stream):
  //   R1: q -> z[0:8M)     R2: k -> y_bn(bf16) -> z[8M:16M)
  //   R3: vT               R4: ctx -> ffn hidden f1
  us* qb_ = (us*)take(16384ull * 512 * 2);       // R1
  us* kb_ = (us*)take(16384ull * 512 * 2);       // R2 (contiguous after R1)
  us* vt = (us*)take(16384ull * 512 * 2);        // R3
  us* bigR4 = (us*)take(33554432ull * 2);        // R4
  float* gsum = (float*)take(512 * 4);
  float* gsumsq = (float*)take(512 * 4);
  float* feat = (float*)take(2048 * 4);
  us* ctxb = bigR4;        // R4 (ctx live attn -> Wo; must NOT alias q/k/vt:
                           //     fused attn reads q,k,vt while writing ctx)
  us* f1 = bigR4;          // R4 reuse (ctx dead after Wo; f1 written by FFN1)
  us* ybb = kb_;           // alias R2 (k dead after attn_kernel)
  float* zb = (float*)qb_; // alias R1+R2 (q dead after attn, ybb dead after FFN1;
                           //     NOTE: FFN2 must NOT read ybb — zb overwrites it)

  // Workspace guard: clean diagnostic failure instead of GPU fault if pool
  // is smaller than planned.
  if (off > ws_size) return;

  transpose_bf16<<<dim3(16, 16, 6), 256, 0, stream>>>(Wq, qkvT, 512, 512,
                                                      262144, 786432);
  transpose_bf16<<<dim3(16, 16, 6), 256, 0, stream>>>(Wk, qkvT + 262144, 512,
                                                      512, 262144, 786432);
  transpose_bf16<<<dim3(16, 16, 6), 256, 0, stream>>>(Wv, qkvT + 524288, 512,
                                                      512, 262144, 786432);
  transpose_bf16<<<dim3(16, 16, 6), 256, 0, stream>>>(Wo, WoT, 512, 512,
                                                      262144, 262144);
  transpose_bf16<<<dim3(16, 64, 6), 256, 0, stream>>>(W1, W1T, 512, 2048,
                                                      1048576, 1048576);
  transpose_bf16<<<dim3(64, 16, 6), 256, 0, stream>>>(W2, W2T, 2048, 512,
                                                      1048576, 1048576);
  transpose_bf16<<<dim3(4096, 1, 1), 256, 0, stream>>>(Wf, WfT, 131072, 32,
                                                       0, 0);
  embed_kernel<<<2048, 256, 0, stream>>>(state, W_emb, b_emb, pes, h, hb);

  for (int l = 0; l < 6; ++l) {
    const us* qkvTl = qkvT + (size_t)l * 786432;
    const us* WoTl = WoT + (size_t)l * 262144;
    const us* W1Tl = W1T + (size_t)l * 1048576;
    const us* W2Tl = W2T + (size_t)l * 1048576;

    // fused QKV: N=1536, writes q, k, and v-transposed in one pass
    gemm_bt<128, 128, 64, 64, EPI_QKV><<<dim3(128, 12, 1), 256, 0, stream>>>(
        hb, 512, 0, qkvTl, 512, 0, qb_, kb_, vt, 512, bq + l * 512,
        nullptr, nullptr, nullptr, bk + l * 512, bv + l * 512, 512);
    // fused attention v2: QK^T + reg-softmax + PV -> ctx
    attn_kernel<<<dim3(2, 512), 256, 0, stream>>>(qb_, kb_, vt, ctxb);
    gemm_bt<128, 128, 64, 64, EPI_RESID_F32><<<dim3(128, 4, 1), 256, 0, stream>>>(
        ctxb, 512, 0, WoTl, 512, 0, y, nullptr, nullptr, 512, bo + l * 512,
        h, nullptr, nullptr, nullptr, nullptr, 512);
    zerof<<<4, 256, 0, stream>>>(gsum, 1024);  // gsum+gsumsq contiguous
    bn_stats<<<256, 256, 0, stream>>>(y, gsum, gsumsq);
    bn_apply<<<8192, 256, 0, stream>>>(y, gsum, gsumsq, bn_g + l * 512,
                                       bn_b + l * 512, ybb);
    gemm_bt<128, 128, 64, 64, EPI_RELU_BF16><<<dim3(128, 16, 1), 256, 0, stream>>>(
        ybb, 512, 0, W1Tl, 512, 0, f1, nullptr, nullptr, 2048, b1 + l * 2048,
        nullptr, nullptr, nullptr, nullptr, nullptr, 512);
    gemm_bt<128, 128, 64, 64, EPI_FFN2_F32><<<dim3(128, 4, 1), 256, 0, stream>>>(
        f1, 2048, 0, W2Tl, 2048, 0, zb, nullptr, nullptr, 512, b2 + l * 512,
        y, gsum, gsumsq, bn_g + l * 512, bn_b + l * 512, 2048);
    ln_kernel<<<16384, 128, 0, stream>>>(zb, ln_g + l * 512, ln_b + l * 512, h, hb);
  }

  // feat = flat @ Wf: plain GEMM M=64,N=32,K=131072 (flat rows are contiguous
  // hb slices), split-K over 128 chunks of 1024, fp32 atomic accumulate.
  zerof<<<8, 256, 0, stream>>>(feat, 2048);
  gemm_bt<64, 32, 32, 16, EPI_FEAT><<<dim3(1, 1, 128), 256, 0, stream>>>(
      hb, 131072, 1024, WfT, 131072, 1024, feat, nullptr, nullptr, 32,
      nullptr, nullptr, nullptr, nullptr, nullptr, nullptr, 1024);
  final_head<<<1, 320, 0, stream>>>(feat, bf_, action, Wfin, bfin, out);
}

// Round 8
// 1692.200 us; speedup vs baseline: 1.1968x; 1.0415x over previous
//
#include <hip/hip_runtime.h>

typedef short bf16x8 __attribute__((ext_vector_type(8)));
typedef float f32x4 __attribute__((ext_vector_type(4)));
typedef unsigned short us;

#define BN_EPS 1e-3f

// fp32 -> bf16 round-to-nearest-even (no NaN inputs in this net)
static __device__ __forceinline__ us f2bs(float x) {
  unsigned int u = __builtin_bit_cast(unsigned int, x);
  unsigned int r = (u + 0x7FFFu + ((u >> 16) & 1u)) >> 16;
  return (us)r;
}

// async global->LDS, 16B per lane; LDS dest is wave-uniform base + lane*16.
static __device__ __forceinline__ void gl_lds16(const us* g, us* l) {
  __builtin_amdgcn_global_load_lds(
      (const __attribute__((address_space(1))) void*)g,
      (__attribute__((address_space(3))) void*)l, 16, 0, 0);
}

// ---------------- transpose + fp32->bf16: src [K,N] f32 -> dst [N,K] bf16 ----
__global__ __launch_bounds__(256) void transpose_bf16(
    const float* __restrict__ src, us* __restrict__ dst, int K, int N,
    long sstride, long dstride) {
  long sbs = (long)blockIdx.z * sstride;
  long sbd = (long)blockIdx.z * dstride;
  __shared__ float tile[32][33];
  int tx = threadIdx.x & 31, ty = threadIdx.x >> 5;  // 32 x 8
  int k0 = blockIdx.x * 32, n0 = blockIdx.y * 32;
  for (int i = 0; i < 32; i += 8)
    tile[ty + i][tx] = src[sbs + (long)(k0 + ty + i) * N + n0 + tx];
  __syncthreads();
  for (int i = 0; i < 32; i += 8)
    dst[sbd + (long)(n0 + ty + i) * K + k0 + tx] = f2bs(tile[tx][ty + i]);
}

// ---------------- embedding: h = state @ Wemb + bemb + pes; hb = bf16(h) ----
__global__ __launch_bounds__(256) void embed_kernel(
    const float* __restrict__ state, const float* __restrict__ Wemb,
    const float* __restrict__ bemb, const float* __restrict__ pes,
    float* __restrict__ h, us* __restrict__ hb) {
  int t = threadIdx.x;
  int row0 = blockIdx.x * 8;
  __shared__ float st[8][64];
  {
    int i = t;
    st[i >> 6][i & 63] = state[(long)row0 * 64 + i];
    i += 256;
    st[i >> 6][i & 63] = state[(long)row0 * 64 + i];
  }
  __syncthreads();
  int c0 = t, c1 = t + 256;
  float acc0[8], acc1[8];
#pragma unroll
  for (int r = 0; r < 8; ++r) { acc0[r] = 0.f; acc1[r] = 0.f; }
  for (int kk = 0; kk < 64; ++kk) {
    float w0 = Wemb[kk * 512 + c0], w1 = Wemb[kk * 512 + c1];
#pragma unroll
    for (int r = 0; r < 8; ++r) {
      acc0[r] += st[r][kk] * w0;
      acc1[r] += st[r][kk] * w1;
    }
  }
  float be0 = bemb[c0], be1 = bemb[c1];
#pragma unroll
  for (int r = 0; r < 8; ++r) {
    int row = row0 + r, s = row & 255;
    float v0 = acc0[r] + be0 + pes[(long)s * 512 + c0];
    float v1 = acc1[r] + be1 + pes[(long)s * 512 + c1];
    h[(long)row * 512 + c0] = v0;
    h[(long)row * 512 + c1] = v1;
    hb[(long)row * 512 + c0] = f2bs(v0);
    hb[(long)row * 512 + c1] = f2bs(v1);
  }
}

// ---------------- generic bf16 MFMA GEMM, B given transposed [N,K] ----------
// Staging: global_load_lds width=16, linear LDS [BM][64] (BK=64), 2-barrier
// K-loop (m97 structure). 128x128 tile is the verified sweet spot (R6 lesson).
// R8: bf16 outputs staged through LDS (As/Bs reused as C-tile) for uint4
// coalesced global writes; V^T packs 4 consecutive s-rows into ushort4.
enum { EPI_QKV = 0, EPI_RESID_F32 = 1, EPI_RELU_BF16 = 2, EPI_FFN2_F32 = 3,
       EPI_FEAT = 4 };

template <int BM, int BN, int WM, int WN, int EPI>
__global__ __launch_bounds__((BM / WM) * (BN / WN) * 64)
void gemm_bt(const us* __restrict__ A, int lda, long batchA,
             const us* __restrict__ Bt, int ldb, long batchB,
             void* __restrict__ Cout, void* __restrict__ C2,
             void* __restrict__ C3, int ldc,
             const float* __restrict__ bias,
             const float* __restrict__ resid,
             const float* __restrict__ gsum, const float* __restrict__ gsumsq,
             const float* __restrict__ gamma, const float* __restrict__ beta,
             int K) {
  constexpr int WCols = BN / WN;
  constexpr int NT = (BM / WM) * (BN / WN) * 64;
  constexpr int NW = NT / 64;
  constexpr int MI = WM / 16, NI = WN / 16;
  constexpr int LA = BM / 8;  // 1KB wave-loads to fill A tile (8 rows each)
  constexpr int LB = BN / 8;
  const int tid = threadIdx.x;
  const int w = tid >> 6, l = tid & 63;
  const int wr = w / WCols, wc = w % WCols;
  const int lr = l & 15, lh = l >> 4;
  const int z = blockIdx.z;
  const long m0 = (long)blockIdx.x * BM;
  const long n0 = (long)blockIdx.y * BN;
  A += (long)z * batchA;
  Bt += (long)z * batchB;
  __shared__ __align__(16) us smem[BM * 64 + BN * 64];
  us* Asm = smem;            // [BM][64]
  us* Bsm = smem + BM * 64;  // [BN][64]
  // per-lane source offsets for the async staging loads
  const int srow = l >> 3, scol = (l & 7) << 3;
  f32x4 acc[MI][NI] = {};
  for (int kt = 0; kt < K; kt += 64) {
    __syncthreads();  // previous tile's reads complete before overwrite
    for (int j = w; j < LA; j += NW) {
      int rb = j * 8;
      gl_lds16(A + (m0 + rb + srow) * lda + kt + scol, Asm + rb * 64);
    }
    for (int j = w; j < LB; j += NW) {
      int rb = j * 8;
      gl_lds16(Bt + (n0 + rb + srow) * ldb + kt + scol, Bsm + rb * 64);
    }
    asm volatile("s_waitcnt vmcnt(0)" ::: "memory");
    __syncthreads();
#pragma unroll
    for (int kk = 0; kk < 64; kk += 32) {
      bf16x8 af[MI], bfr[NI];
#pragma unroll
      for (int mi = 0; mi < MI; ++mi)
        af[mi] = *(const bf16x8*)&Asm[(wr * WM + mi * 16 + lr) * 64 + kk + lh * 8];
#pragma unroll
      for (int ni = 0; ni < NI; ++ni)
        bfr[ni] = *(const bf16x8*)&Bsm[(wc * WN + ni * 16 + lr) * 64 + kk + lh * 8];
#pragma unroll
      for (int mi = 0; mi < MI; ++mi)
#pragma unroll
        for (int ni = 0; ni < NI; ++ni)
          acc[mi][ni] = __builtin_amdgcn_mfma_f32_16x16x32_bf16(
              af[mi], bfr[ni], acc[mi][ni], 0, 0, 0);
    }
  }

  if constexpr (EPI == EPI_QKV) {
    const int seg = (int)(n0 >> 9);  // uniform per block (128 | 512)
    const int nc0 = (int)(n0 & 511);
    if (seg == 2) {
      // V^T: 4 consecutive s-rows (q_) at fixed dh are contiguous -> ushort4
#pragma unroll
      for (int mi = 0; mi < MI; ++mi) {
#pragma unroll
        for (int ni = 0; ni < NI; ++ni) {
          const int segc = nc0 + wc * WN + ni * 16 + lr;
          const float bv_ = beta[segc];  // bv bias
          ushort4 pv;
#pragma unroll
          for (int q_ = 0; q_ < 4; ++q_)
            ((us*)&pv)[q_] = f2bs(acc[mi][ni][q_] + bv_);
          const long row0g = m0 + wr * WM + mi * 16 + lh * 4;
          const long o = (((row0g >> 8) * 8 + (segc >> 6)) * 64 + (segc & 63)) *
                             256 + (row0g & 255);
          *(ushort4*)&((us*)C3)[o] = pv;
        }
      }
    } else {
      // q/k: stage C-tile in LDS (reuses As/Bs: 128*128 us = 32KB exactly)
      __syncthreads();
#pragma unroll
      for (int mi = 0; mi < MI; ++mi)
#pragma unroll
        for (int ni = 0; ni < NI; ++ni) {
          const int cl = wc * WN + ni * 16 + lr;
          const float bv_ = seg == 0 ? bias[nc0 + cl] : gamma[nc0 + cl];
#pragma unroll
          for (int q_ = 0; q_ < 4; ++q_) {
            const int rl = wr * WM + mi * 16 + lh * 4 + q_;
            smem[rl * BN + cl] = f2bs(acc[mi][ni][q_] + bv_);
          }
        }
      __syncthreads();
      us* dstp = seg == 0 ? (us*)Cout : (us*)C2;
      for (int i = tid; i < (BM * BN) / 8; i += NT) {
        const int idx = i * 8;
        const int row = idx / BN, colc = idx % BN;
        *(uint4*)&dstp[(m0 + row) * 512 + nc0 + colc] = *(uint4*)&smem[idx];
      }
    }
  } else if constexpr (EPI == EPI_RELU_BF16 && BM == 128 && BN == 128) {
    // f1: staged coalesced write
    __syncthreads();
#pragma unroll
    for (int mi = 0; mi < MI; ++mi)
#pragma unroll
      for (int ni = 0; ni < NI; ++ni) {
        const int cl = wc * WN + ni * 16 + lr;
        const float bv_ = bias[(int)n0 + cl];
#pragma unroll
        for (int q_ = 0; q_ < 4; ++q_) {
          const int rl = wr * WM + mi * 16 + lh * 4 + q_;
          smem[rl * BN + cl] = f2bs(fmaxf(acc[mi][ni][q_] + bv_, 0.f));
        }
      }
    __syncthreads();
    for (int i = tid; i < (BM * BN) / 8; i += NT) {
      const int idx = i * 8;
      const int row = idx / BN, colc = idx % BN;
      *(uint4*)&((us*)Cout)[(m0 + row) * ldc + n0 + colc] = *(uint4*)&smem[idx];
    }
  } else {
    // f32 epilogues (+ feat atomics)
#pragma unroll
    for (int mi = 0; mi < MI; ++mi) {
#pragma unroll
      for (int ni = 0; ni < NI; ++ni) {
        const int col = (int)n0 + wc * WN + ni * 16 + lr;
        float bv_ = 0.f;
        if constexpr (EPI != EPI_FEAT) bv_ = bias[col];
        float aa = 0.f, bb2 = 0.f;
        if constexpr (EPI == EPI_FFN2_F32) {
          const float invN = 1.f / 16384.f;
          float mu = gsum[col] * invN;
          float var = gsumsq[col] * invN - mu * mu;
          aa = gamma[col] * rsqrtf(var + BN_EPS);
          bb2 = beta[col] - mu * aa;
        }
#pragma unroll
        for (int q_ = 0; q_ < 4; ++q_) {
          const long row = m0 + wr * WM + mi * 16 + lh * 4 + q_;
          float v = acc[mi][ni][q_] + bv_;
          if constexpr (EPI == EPI_RESID_F32) {
            ((float*)Cout)[row * ldc + col] = v + resid[row * ldc + col];
          } else if constexpr (EPI == EPI_FEAT) {
            atomicAdd(&((float*)Cout)[row * ldc + col], v);
          } else if constexpr (EPI == EPI_FFN2_F32) {
            float ybn = resid[row * ldc + col] * aa + bb2;
            ((float*)Cout)[row * ldc + col] = ybn + v;
          }
        }
      }
    }
  }
}

// ---------------- fused attention v2: QK^T*scale + reg-softmax + PV ---------
// grid (2, B*H): each block owns one (b,h) half — 4 q-tiles of 32 rows.
__global__ __launch_bounds__(256) void attn_kernel(
    const us* __restrict__ q, const us* __restrict__ k,
    const us* __restrict__ vt, us* __restrict__ ctx) {
  const int half = blockIdx.x;  // 0..1
  const int z = blockIdx.y;     // b*8+h
  const int b = z >> 3, hh = z & 7;
  const long qkBase = (long)b * 131072 + hh * 64;
  const int tid = threadIdx.x, w = tid >> 6, l = tid & 63;
  const int lr = l & 15, lh = l >> 4;
  __shared__ __align__(16) us Qs[32][72];
  __shared__ __align__(16) us Ks[64][72];   // K chunk, reused for V chunks
  __shared__ __align__(16) us Pb[32][264];  // normalized P (bf16)
  __shared__ float fred[32][2];             // cross-wave row max/sum exchange
  const int qr = (w >> 1) * 16, qc = (w & 1) * 32;
  const us* vb = vt + (long)z * 16384;
  const int ldr = tid >> 3, ldc = (tid & 7) << 3;

  for (int qi = 0; qi < 4; ++qi) {
    const int qb = half * 4 + qi;
    *(uint4*)&Qs[ldr][ldc] =
        *(const uint4*)(q + qkBase + (long)(qb * 32 + ldr) * 512 + ldc);
    f32x4 sacc[4][2] = {};
    for (int skb = 0; skb < 4; ++skb) {
      __syncthreads();  // Ks overwrite safe + Qs visible (skb==0)
      for (int i = tid; i < 512; i += 256) {
        int r = i >> 3, c = (i & 7) << 3;
        *(uint4*)&Ks[r][c] =
            *(const uint4*)(k + qkBase + (long)(skb * 64 + r) * 512 + c);
      }
      __syncthreads();
#pragma unroll
      for (int kh = 0; kh < 2; ++kh) {
        bf16x8 aq = *(const bf16x8*)&Qs[qr + lr][kh * 32 + lh * 8];
#pragma unroll
        for (int ni = 0; ni < 2; ++ni) {
          bf16x8 bkk = *(const bf16x8*)&Ks[qc + ni * 16 + lr][kh * 32 + lh * 8];
          sacc[skb][ni] = __builtin_amdgcn_mfma_f32_16x16x32_bf16(
              aq, bkk, sacc[skb][ni], 0, 0, 0);
        }
      }
    }
    // ---- softmax in registers ----
    float m0[4] = {-1e30f, -1e30f, -1e30f, -1e30f};
#pragma unroll
    for (int skb = 0; skb < 4; ++skb)
#pragma unroll
      for (int ni = 0; ni < 2; ++ni)
#pragma unroll
        for (int q_ = 0; q_ < 4; ++q_) {
          float v = sacc[skb][ni][q_] * 0.125f;
          sacc[skb][ni][q_] = v;
          m0[q_] = fmaxf(m0[q_], v);
        }
#pragma unroll
    for (int off = 1; off < 16; off <<= 1)
#pragma unroll
      for (int q_ = 0; q_ < 4; ++q_)
        m0[q_] = fmaxf(m0[q_], __shfl_xor(m0[q_], off));
    if (lr == 0) {
#pragma unroll
      for (int q_ = 0; q_ < 4; ++q_) fred[qr + lh * 4 + q_][w & 1] = m0[q_];
    }
    __syncthreads();
#pragma unroll
    for (int q_ = 0; q_ < 4; ++q_) {
      int row = qr + lh * 4 + q_;
      m0[q_] = fmaxf(fred[row][0], fred[row][1]);
    }
    float s0[4] = {0.f, 0.f, 0.f, 0.f};
#pragma unroll
    for (int skb = 0; skb < 4; ++skb)
#pragma unroll
      for (int ni = 0; ni < 2; ++ni)
#pragma unroll
        for (int q_ = 0; q_ < 4; ++q_) {
          float e = __expf(sacc[skb][ni][q_] - m0[q_]);
          sacc[skb][ni][q_] = e;
          s0[q_] += e;
        }
#pragma unroll
    for (int off = 1; off < 16; off <<= 1)
#pragma unroll
      for (int q_ = 0; q_ < 4; ++q_) s0[q_] += __shfl_xor(s0[q_], off);
    __syncthreads();  // max-reads of fred done before sum overwrite
    if (lr == 0) {
#pragma unroll
      for (int q_ = 0; q_ < 4; ++q_) fred[qr + lh * 4 + q_][w & 1] = s0[q_];
    }
    __syncthreads();
#pragma unroll
    for (int q_ = 0; q_ < 4; ++q_) {
      int row = qr + lh * 4 + q_;
      s0[q_] = 1.f / (fred[row][0] + fred[row][1]);
    }
    // normalized P -> LDS bf16 (MFMA A-fragment transpose)
#pragma unroll
    for (int skb = 0; skb < 4; ++skb)
#pragma unroll
      for (int ni = 0; ni < 2; ++ni)
#pragma unroll
        for (int q_ = 0; q_ < 4; ++q_)
          Pb[qr + lh * 4 + q_][skb * 64 + qc + ni * 16 + lr] =
              f2bs(sacc[skb][ni][q_] * s0[q_]);
    // ---- PV: C[32 q][64 d] = P[32][256] x V[256][64] via V^T tiles ----
    f32x4 pacc[2] = {};
    for (int kc = 0; kc < 256; kc += 64) {
      __syncthreads();  // Pb visible (kc==0); prior Ks reads done
      for (int i = tid; i < 512; i += 256) {
        int r = i >> 3, c = (i & 7) << 3;
        *(uint4*)&Ks[r][c] = *(const uint4*)(vb + (long)r * 256 + kc + c);
      }
      __syncthreads();
#pragma unroll
      for (int kh = 0; kh < 2; ++kh) {
        bf16x8 ap = *(const bf16x8*)&Pb[qr + lr][kc + kh * 32 + lh * 8];
#pragma unroll
        for (int ni = 0; ni < 2; ++ni) {
          bf16x8 bv2 = *(const bf16x8*)&Ks[qc + ni * 16 + lr][kh * 32 + lh * 8];
          pacc[ni] = __builtin_amdgcn_mfma_f32_16x16x32_bf16(
              ap, bv2, pacc[ni], 0, 0, 0);
        }
      }
    }
    const long cb2 = ((long)(b * 256 + qb * 32)) * 512 + hh * 64;
#pragma unroll
    for (int ni = 0; ni < 2; ++ni)
#pragma unroll
      for (int q_ = 0; q_ < 4; ++q_) {
        int row = qr + lh * 4 + q_;
        int col = qc + ni * 16 + lr;
        ctx[cb2 + (long)row * 512 + col] = f2bs(pacc[ni][q_]);
      }
  }
}

// ---------------- BN stats / apply ------------------------------------------
__global__ __launch_bounds__(256) void bn_stats(const float* __restrict__ y,
                                                float* __restrict__ gsum,
                                                float* __restrict__ gsumsq) {
  int t = threadIdx.x;
  long base = (long)blockIdx.x * 64 * 512;
  float s0 = 0, q0 = 0, s1 = 0, q1 = 0;
  for (int r = 0; r < 64; ++r) {
    float v0 = y[base + r * 512 + t];
    float v1 = y[base + r * 512 + t + 256];
    s0 += v0; q0 += v0 * v0;
    s1 += v1; q1 += v1 * v1;
  }
  atomicAdd(&gsum[t], s0);
  atomicAdd(&gsumsq[t], q0);
  atomicAdd(&gsum[t + 256], s1);
  atomicAdd(&gsumsq[t + 256], q1);
}

__global__ __launch_bounds__(256) void bn_apply(
    const float* __restrict__ y, const float* __restrict__ gsum,
    const float* __restrict__ gsumsq, const float* __restrict__ gamma,
    const float* __restrict__ beta, us* __restrict__ ybb) {
  long i4 = (long)blockIdx.x * 256 + threadIdx.x;
  long e = i4 * 4;
  int c = (int)(e & 511);
  const float invN = 1.f / 16384.f;
  float4 v = *(const float4*)(y + e);
  float vv[4] = {v.x, v.y, v.z, v.w};
  ushort4 r;
  us* rp = (us*)&r;
#pragma unroll
  for (int j = 0; j < 4; ++j) {
    int cj = c + j;
    float mu = gsum[cj] * invN;
    float var = gsumsq[cj] * invN - mu * mu;
    float a = gamma[cj] * rsqrtf(var + BN_EPS);
    float b = beta[cj] - mu * a;
    rp[j] = f2bs(vv[j] * a + b);
  }
  *(ushort4*)(ybb + e) = r;
}

// ---------------- LayerNorm per row -> h (f32) + hb (bf16) ------------------
__global__ __launch_bounds__(128) void ln_kernel(
    const float* __restrict__ zin, const float* __restrict__ g,
    const float* __restrict__ b, float* __restrict__ hout,
    us* __restrict__ hb) {
  int r = blockIdx.x, t = threadIdx.x;
  const float* zr = zin + (long)r * 512;
  float4 v = *(const float4*)(zr + t * 4);
  float s = v.x + v.y + v.z + v.w;
  float qs = v.x * v.x + v.y * v.y + v.z * v.z + v.w * v.w;
  for (int off = 32; off >= 1; off >>= 1) {
    s += __shfl_down(s, off);
    qs += __shfl_down(qs, off);
  }
  __shared__ float ls[2], lq[2];
  if ((t & 63) == 0) {
    ls[t >> 6] = s;
    lq[t >> 6] = qs;
  }
  __syncthreads();
  float mu = (ls[0] + ls[1]) * (1.f / 512.f);
  float var = (lq[0] + lq[1]) * (1.f / 512.f) - mu * mu;
  float rs = rsqrtf(var + BN_EPS);
  float4 gg = *(const float4*)(g + t * 4);
  float4 bb = *(const float4*)(b + t * 4);
  float o0 = gg.x * (v.x - mu) * rs + bb.x;
  float o1 = gg.y * (v.y - mu) * rs + bb.y;
  float o2 = gg.z * (v.z - mu) * rs + bb.z;
  float o3 = gg.w * (v.w - mu) * rs + bb.w;
  *(float4*)(hout + (long)r * 512 + t * 4) = make_float4(o0, o1, o2, o3);
  ushort4 hv;
  us* hp = (us*)&hv;
  hp[0] = f2bs(o0); hp[1] = f2bs(o1); hp[2] = f2bs(o2); hp[3] = f2bs(o3);
  *(ushort4*)(hb + (long)r * 512 + t * 4) = hv;
}

// ---------------- head ------------------------------------------------------
__global__ void zerof(float* __restrict__ p, int n) {
  int i = blockIdx.x * 256 + threadIdx.x;
  if (i < n) p[i] = 0.f;
}

__global__ __launch_bounds__(320) void final_head(
    const float* __restrict__ feat, const float* __restrict__ bf_,
    const float* __restrict__ action, const float* __restrict__ Wfin,
    const float* __restrict__ bfin, float* __restrict__ out) {
  int t = threadIdx.x;
  int b = t & 63, o = t >> 6;  // 64 x 5
  float acc = bfin[o];
  for (int j = 0; j < 32; ++j) acc += (feat[b * 32 + j] + bf_[j]) * Wfin[j * 5 + o];
  for (int j = 0; j < 8; ++j) acc += action[b * 8 + j] * Wfin[(32 + j) * 5 + o];
  out[b * 5 + o] = acc;
}

// ---------------- host ------------------------------------------------------
extern "C" void kernel_launch(void* const* d_in, const int* in_sizes, int n_in,
                              void* d_out, int out_size, void* d_ws,
                              size_t ws_size, hipStream_t stream) {
  const float* state = (const float*)d_in[0];
  const float* action = (const float*)d_in[1];
  const float* pes = (const float*)d_in[2];
  const float* W_emb = (const float*)d_in[3];
  const float* b_emb = (const float*)d_in[4];
  const float* Wq = (const float*)d_in[5];
  const float* bq = (const float*)d_in[6];
  const float* Wk = (const float*)d_in[7];
  const float* bk = (const float*)d_in[8];
  const float* Wv = (const float*)d_in[9];
  const float* bv = (const float*)d_in[10];
  const float* Wo = (const float*)d_in[11];
  const float* bo = (const float*)d_in[12];
  const float* bn_g = (const float*)d_in[13];
  const float* bn_b = (const float*)d_in[14];
  const float* W1 = (const float*)d_in[15];
  const float* b1 = (const float*)d_in[16];
  const float* W2 = (const float*)d_in[17];
  const float* b2 = (const float*)d_in[18];
  const float* ln_g = (const float*)d_in[19];
  const float* ln_b = (const float*)d_in[20];
  const float* Wf = (const float*)d_in[21];
  const float* bf_ = (const float*)d_in[22];
  const float* Wfin = (const float*)d_in[23];
  const float* bfin = (const float*)d_in[24];
  float* out = (float*)d_out;
  (void)in_sizes; (void)n_in; (void)out_size;

  char* wp = (char*)d_ws;
  size_t off = 0;
  auto take = [&](size_t bytes) {
    void* p = wp + off;
    off += (bytes + 255) & ~(size_t)255;
    return p;
  };
  // Persistent across the whole launch:
  us* qkvT = (us*)take(6ull * 1536 * 512 * 2);  // [l][{q,k,v}*512][512]
  us* WoT = (us*)take(6ull * 512 * 512 * 2);
  us* W1T = (us*)take(6ull * 2048 * 512 * 2);
  us* W2T = (us*)take(6ull * 512 * 2048 * 2);
  us* WfT = (us*)take(32ull * 131072 * 2);      // [32][131072]
  float* h = (float*)take(16384ull * 512 * 4);   // f32 activations (resid)
  us* hb = (us*)take(16384ull * 512 * 2);        // bf16 copy of h
  float* y = (float*)take(16384ull * 512 * 4);   // attn-block output (pre-BN)
  // Aliased regions (lifetime analysis; all transitions write-after-last-read
  // on the same stream):
  //   R1: q -> z[0:8M)     R2: k -> y_bn(bf16) -> z[8M:16M)
  //   R3: vT               R4: ctx -> ffn hidden f1
  us* qb_ = (us*)take(16384ull * 512 * 2);       // R1
  us* kb_ = (us*)take(16384ull * 512 * 2);       // R2 (contiguous after R1)
  us* vt = (us*)take(16384ull * 512 * 2);        // R3
  us* bigR4 = (us*)take(33554432ull * 2);        // R4
  float* gsum = (float*)take(512 * 4);
  float* gsumsq = (float*)take(512 * 4);
  float* feat = (float*)take(2048 * 4);
  us* ctxb = bigR4;        // R4 (ctx live attn -> Wo; must NOT alias q/k/vt)
  us* f1 = bigR4;          // R4 reuse (ctx dead after Wo; f1 written by FFN1)
  us* ybb = kb_;           // alias R2 (k dead after attn_kernel)
  float* zb = (float*)qb_; // alias R1+R2 (q dead after attn, ybb dead after FFN1)

  // Workspace guard: clean diagnostic failure instead of GPU fault.
  if (off > ws_size) return;

  transpose_bf16<<<dim3(16, 16, 6), 256, 0, stream>>>(Wq, qkvT, 512, 512,
                                                      262144, 786432);
  transpose_bf16<<<dim3(16, 16, 6), 256, 0, stream>>>(Wk, qkvT + 262144, 512,
                                                      512, 262144, 786432);
  transpose_bf16<<<dim3(16, 16, 6), 256, 0, stream>>>(Wv, qkvT + 524288, 512,
                                                      512, 262144, 786432);
  transpose_bf16<<<dim3(16, 16, 6), 256, 0, stream>>>(Wo, WoT, 512, 512,
                                                      262144, 262144);
  transpose_bf16<<<dim3(16, 64, 6), 256, 0, stream>>>(W1, W1T, 512, 2048,
                                                      1048576, 1048576);
  transpose_bf16<<<dim3(64, 16, 6), 256, 0, stream>>>(W2, W2T, 2048, 512,
                                                      1048576, 1048576);
  transpose_bf16<<<dim3(4096, 1, 1), 256, 0, stream>>>(Wf, WfT, 131072, 32,
                                                       0, 0);
  embed_kernel<<<2048, 256, 0, stream>>>(state, W_emb, b_emb, pes, h, hb);

  for (int l = 0; l < 6; ++l) {
    const us* qkvTl = qkvT + (size_t)l * 786432;
    const us* WoTl = WoT + (size_t)l * 262144;
    const us* W1Tl = W1T + (size_t)l * 1048576;
    const us* W2Tl = W2T + (size_t)l * 1048576;

    // fused QKV: N=1536, writes q, k, and v-transposed in one pass
    gemm_bt<128, 128, 64, 64, EPI_QKV><<<dim3(128, 12, 1), 256, 0, stream>>>(
        hb, 512, 0, qkvTl, 512, 0, qb_, kb_, vt, 512, bq + l * 512,
        nullptr, nullptr, nullptr, bk + l * 512, bv + l * 512, 512);
    // fused attention v2: QK^T + reg-softmax + PV -> ctx
    attn_kernel<<<dim3(2, 512), 256, 0, stream>>>(qb_, kb_, vt, ctxb);
    gemm_bt<128, 128, 64, 64, EPI_RESID_F32><<<dim3(128, 4, 1), 256, 0, stream>>>(
        ctxb, 512, 0, WoTl, 512, 0, y, nullptr, nullptr, 512, bo + l * 512,
        h, nullptr, nullptr, nullptr, nullptr, 512);
    zerof<<<4, 256, 0, stream>>>(gsum, 1024);  // gsum+gsumsq contiguous
    bn_stats<<<256, 256, 0, stream>>>(y, gsum, gsumsq);
    bn_apply<<<8192, 256, 0, stream>>>(y, gsum, gsumsq, bn_g + l * 512,
                                       bn_b + l * 512, ybb);
    gemm_bt<128, 128, 64, 64, EPI_RELU_BF16><<<dim3(128, 16, 1), 256, 0, stream>>>(
        ybb, 512, 0, W1Tl, 512, 0, f1, nullptr, nullptr, 2048, b1 + l * 2048,
        nullptr, nullptr, nullptr, nullptr, nullptr, 512);
    gemm_bt<128, 128, 64, 64, EPI_FFN2_F32><<<dim3(128, 4, 1), 256, 0, stream>>>(
        f1, 2048, 0, W2Tl, 2048, 0, zb, nullptr, nullptr, 512, b2 + l * 512,
        y, gsum, gsumsq, bn_g + l * 512, bn_b + l * 512, 2048);
    ln_kernel<<<16384, 128, 0, stream>>>(zb, ln_g + l * 512, ln_b + l * 512, h, hb);
  }

  // feat = flat @ Wf: split-K over 128 chunks of 1024, fp32 atomic accumulate.
  zerof<<<8, 256, 0, stream>>>(feat, 2048);
  gemm_bt<64, 32, 32, 16, EPI_FEAT><<<dim3(1, 1, 128), 256, 0, stream>>>(
      hb, 131072, 1024, WfT, 131072, 1024, feat, nullptr, nullptr, 32,
      nullptr, nullptr, nullptr, nullptr, nullptr, nullptr, 1024);
  final_head<<<1, 320, 0, stream>>>(feat, bf_, action, Wfin, bfin, out);
}

// Round 9
// 1634.250 us; speedup vs baseline: 1.2393x; 1.0355x over previous
//
#include <hip/hip_runtime.h>

typedef short bf16x8 __attribute__((ext_vector_type(8)));
typedef float f32x4 __attribute__((ext_vector_type(4)));
typedef unsigned short us;

#define BN_EPS 1e-3f

// fp32 -> bf16 round-to-nearest-even (no NaN inputs in this net)
static __device__ __forceinline__ us f2bs(float x) {
  unsigned int u = __builtin_bit_cast(unsigned int, x);
  unsigned int r = (u + 0x7FFFu + ((u >> 16) & 1u)) >> 16;
  return (us)r;
}
static __device__ __forceinline__ float b2f(us v) {
  unsigned int u = (unsigned int)v << 16;
  return __builtin_bit_cast(float, u);
}

// async global->LDS, 16B per lane; LDS dest is wave-uniform base + lane*16.
static __device__ __forceinline__ void gl_lds16(const us* g, us* l) {
  __builtin_amdgcn_global_load_lds(
      (const __attribute__((address_space(1))) void*)g,
      (__attribute__((address_space(3))) void*)l, 16, 0, 0);
}

// ---------------- transpose + fp32->bf16: src [K,N] f32 -> dst [N,K] bf16 ----
__global__ __launch_bounds__(256) void transpose_bf16(
    const float* __restrict__ src, us* __restrict__ dst, int K, int N,
    long sstride, long dstride) {
  long sbs = (long)blockIdx.z * sstride;
  long sbd = (long)blockIdx.z * dstride;
  __shared__ float tile[32][33];
  int tx = threadIdx.x & 31, ty = threadIdx.x >> 5;  // 32 x 8
  int k0 = blockIdx.x * 32, n0 = blockIdx.y * 32;
  for (int i = 0; i < 32; i += 8)
    tile[ty + i][tx] = src[sbs + (long)(k0 + ty + i) * N + n0 + tx];
  __syncthreads();
  for (int i = 0; i < 32; i += 8)
    dst[sbd + (long)(n0 + ty + i) * K + k0 + tx] = f2bs(tile[tx][ty + i]);
}

// ---------------- embedding: hb = bf16(state @ Wemb + bemb + pes) -----------
__global__ __launch_bounds__(256) void embed_kernel(
    const float* __restrict__ state, const float* __restrict__ Wemb,
    const float* __restrict__ bemb, const float* __restrict__ pes,
    us* __restrict__ hb) {
  int t = threadIdx.x;
  int row0 = blockIdx.x * 8;
  __shared__ float st[8][64];
  {
    int i = t;
    st[i >> 6][i & 63] = state[(long)row0 * 64 + i];
    i += 256;
    st[i >> 6][i & 63] = state[(long)row0 * 64 + i];
  }
  __syncthreads();
  int c0 = t, c1 = t + 256;
  float acc0[8], acc1[8];
#pragma unroll
  for (int r = 0; r < 8; ++r) { acc0[r] = 0.f; acc1[r] = 0.f; }
  for (int kk = 0; kk < 64; ++kk) {
    float w0 = Wemb[kk * 512 + c0], w1 = Wemb[kk * 512 + c1];
#pragma unroll
    for (int r = 0; r < 8; ++r) {
      acc0[r] += st[r][kk] * w0;
      acc1[r] += st[r][kk] * w1;
    }
  }
  float be0 = bemb[c0], be1 = bemb[c1];
#pragma unroll
  for (int r = 0; r < 8; ++r) {
    int row = row0 + r, s = row & 255;
    hb[(long)row * 512 + c0] = f2bs(acc0[r] + be0 + pes[(long)s * 512 + c0]);
    hb[(long)row * 512 + c1] = f2bs(acc1[r] + be1 + pes[(long)s * 512 + c1]);
  }
}

// ---------------- generic bf16 MFMA GEMM, B given transposed [N,K] ----------
// Staging: global_load_lds width=16, linear LDS [BM][64] (BK=64), 2-barrier
// K-loop (m97 structure). 128x128 tile (R6 lesson). bf16 outputs staged
// through LDS for uint4 coalesced writes (R8). R9: bf16 trunk (y,h resid).
enum { EPI_QKV = 0, EPI_RESID_BF16 = 1, EPI_RELU_BF16 = 2, EPI_FFN2_F32 = 3,
       EPI_FEAT = 4 };

template <int BM, int BN, int WM, int WN, int EPI>
__global__ __launch_bounds__((BM / WM) * (BN / WN) * 64)
void gemm_bt(const us* __restrict__ A, int lda, long batchA,
             const us* __restrict__ Bt, int ldb, long batchB,
             void* __restrict__ Cout, void* __restrict__ C2,
             void* __restrict__ C3, int ldc,
             const float* __restrict__ bias,
             const us* __restrict__ resid,
             const float* __restrict__ gsum, const float* __restrict__ gsumsq,
             const float* __restrict__ gamma, const float* __restrict__ beta,
             int K) {
  constexpr int WCols = BN / WN;
  constexpr int NT = (BM / WM) * (BN / WN) * 64;
  constexpr int NW = NT / 64;
  constexpr int MI = WM / 16, NI = WN / 16;
  constexpr int LA = BM / 8;  // 1KB wave-loads to fill A tile (8 rows each)
  constexpr int LB = BN / 8;
  const int tid = threadIdx.x;
  const int w = tid >> 6, l = tid & 63;
  const int wr = w / WCols, wc = w % WCols;
  const int lr = l & 15, lh = l >> 4;
  const int z = blockIdx.z;
  const long m0 = (long)blockIdx.x * BM;
  const long n0 = (long)blockIdx.y * BN;
  A += (long)z * batchA;
  Bt += (long)z * batchB;
  __shared__ __align__(16) us smem[BM * 64 + BN * 64];
  us* Asm = smem;            // [BM][64]
  us* Bsm = smem + BM * 64;  // [BN][64]
  const int srow = l >> 3, scol = (l & 7) << 3;
  f32x4 acc[MI][NI] = {};
  for (int kt = 0; kt < K; kt += 64) {
    __syncthreads();  // previous tile's reads complete before overwrite
    for (int j = w; j < LA; j += NW) {
      int rb = j * 8;
      gl_lds16(A + (m0 + rb + srow) * lda + kt + scol, Asm + rb * 64);
    }
    for (int j = w; j < LB; j += NW) {
      int rb = j * 8;
      gl_lds16(Bt + (n0 + rb + srow) * ldb + kt + scol, Bsm + rb * 64);
    }
    asm volatile("s_waitcnt vmcnt(0)" ::: "memory");
    __syncthreads();
#pragma unroll
    for (int kk = 0; kk < 64; kk += 32) {
      bf16x8 af[MI], bfr[NI];
#pragma unroll
      for (int mi = 0; mi < MI; ++mi)
        af[mi] = *(const bf16x8*)&Asm[(wr * WM + mi * 16 + lr) * 64 + kk + lh * 8];
#pragma unroll
      for (int ni = 0; ni < NI; ++ni)
        bfr[ni] = *(const bf16x8*)&Bsm[(wc * WN + ni * 16 + lr) * 64 + kk + lh * 8];
#pragma unroll
      for (int mi = 0; mi < MI; ++mi)
#pragma unroll
        for (int ni = 0; ni < NI; ++ni)
          acc[mi][ni] = __builtin_amdgcn_mfma_f32_16x16x32_bf16(
              af[mi], bfr[ni], acc[mi][ni], 0, 0, 0);
    }
  }

  if constexpr (EPI == EPI_QKV) {
    const int seg = (int)(n0 >> 9);  // uniform per block
    const int nc0 = (int)(n0 & 511);
    if (seg == 2) {
      // V^T: 4 consecutive s-rows contiguous -> ushort4
#pragma unroll
      for (int mi = 0; mi < MI; ++mi) {
#pragma unroll
        for (int ni = 0; ni < NI; ++ni) {
          const int segc = nc0 + wc * WN + ni * 16 + lr;
          const float bv_ = beta[segc];  // bv bias
          ushort4 pv;
#pragma unroll
          for (int q_ = 0; q_ < 4; ++q_)
            ((us*)&pv)[q_] = f2bs(acc[mi][ni][q_] + bv_);
          const long row0g = m0 + wr * WM + mi * 16 + lh * 4;
          const long o = (((row0g >> 8) * 8 + (segc >> 6)) * 64 + (segc & 63)) *
                             256 + (row0g & 255);
          *(ushort4*)&((us*)C3)[o] = pv;
        }
      }
    } else {
      // q/k: stage C-tile in LDS, coalesced uint4 writes
      __syncthreads();
#pragma unroll
      for (int mi = 0; mi < MI; ++mi)
#pragma unroll
        for (int ni = 0; ni < NI; ++ni) {
          const int cl = wc * WN + ni * 16 + lr;
          const float bv_ = seg == 0 ? bias[nc0 + cl] : gamma[nc0 + cl];
#pragma unroll
          for (int q_ = 0; q_ < 4; ++q_) {
            const int rl = wr * WM + mi * 16 + lh * 4 + q_;
            smem[rl * BN + cl] = f2bs(acc[mi][ni][q_] + bv_);
          }
        }
      __syncthreads();
      us* dstp = seg == 0 ? (us*)Cout : (us*)C2;
      for (int i = tid; i < (BM * BN) / 8; i += NT) {
        const int idx = i * 8;
        const int row = idx / BN, colc = idx % BN;
        *(uint4*)&dstp[(m0 + row) * 512 + nc0 + colc] = *(uint4*)&smem[idx];
      }
    }
  } else if constexpr ((EPI == EPI_RELU_BF16 || EPI == EPI_RESID_BF16) &&
                       BM == 128 && BN == 128) {
    // bf16 output staged through LDS for coalesced writes
    __syncthreads();
#pragma unroll
    for (int mi = 0; mi < MI; ++mi)
#pragma unroll
      for (int ni = 0; ni < NI; ++ni) {
        const int cl = wc * WN + ni * 16 + lr;
        const float bv_ = bias[(int)n0 + cl];
#pragma unroll
        for (int q_ = 0; q_ < 4; ++q_) {
          const int rl = wr * WM + mi * 16 + lh * 4 + q_;
          float v = acc[mi][ni][q_] + bv_;
          if constexpr (EPI == EPI_RELU_BF16) {
            smem[rl * BN + cl] = f2bs(fmaxf(v, 0.f));
          } else {  // y = ctx@Wo + bias + hb (bf16 trunk residual)
            v += b2f(resid[(m0 + rl) * ldc + (int)n0 + cl]);
            smem[rl * BN + cl] = f2bs(v);
          }
        }
      }
    __syncthreads();
    for (int i = tid; i < (BM * BN) / 8; i += NT) {
      const int idx = i * 8;
      const int row = idx / BN, colc = idx % BN;
      *(uint4*)&((us*)Cout)[(m0 + row) * ldc + n0 + colc] = *(uint4*)&smem[idx];
    }
  } else {
    // f32 epilogues (+ feat atomics)
#pragma unroll
    for (int mi = 0; mi < MI; ++mi) {
#pragma unroll
      for (int ni = 0; ni < NI; ++ni) {
        const int col = (int)n0 + wc * WN + ni * 16 + lr;
        float bv_ = 0.f;
        if constexpr (EPI != EPI_FEAT) bv_ = bias[col];
        float aa = 0.f, bb2 = 0.f;
        if constexpr (EPI == EPI_FFN2_F32) {
          const float invN = 1.f / 16384.f;
          float mu = gsum[col] * invN;
          float var = gsumsq[col] * invN - mu * mu;
          aa = gamma[col] * rsqrtf(var + BN_EPS);
          bb2 = beta[col] - mu * aa;
        }
#pragma unroll
        for (int q_ = 0; q_ < 4; ++q_) {
          const long row = m0 + wr * WM + mi * 16 + lh * 4 + q_;
          float v = acc[mi][ni][q_] + bv_;
          if constexpr (EPI == EPI_FEAT) {
            atomicAdd(&((float*)Cout)[row * ldc + col], v);
          } else if constexpr (EPI == EPI_FFN2_F32) {
            // z = (y_bn) + acc + bias, y read as bf16 trunk
            float ybn = b2f(resid[row * ldc + col]) * aa + bb2;
            ((float*)Cout)[row * ldc + col] = ybn + v;
          }
        }
      }
    }
  }
}

// ---------------- fused attention v2: QK^T*scale + reg-softmax + PV ---------
// grid (2, B*H): each block owns one (b,h) half — 4 q-tiles of 32 rows.
__global__ __launch_bounds__(256) void attn_kernel(
    const us* __restrict__ q, const us* __restrict__ k,
    const us* __restrict__ vt, us* __restrict__ ctx) {
  const int half = blockIdx.x;  // 0..1
  const int z = blockIdx.y;     // b*8+h
  const int b = z >> 3, hh = z & 7;
  const long qkBase = (long)b * 131072 + hh * 64;
  const int tid = threadIdx.x, w = tid >> 6, l = tid & 63;
  const int lr = l & 15, lh = l >> 4;
  __shared__ __align__(16) us Qs[32][72];
  __shared__ __align__(16) us Ks[64][72];   // K chunk, reused for V chunks
  __shared__ __align__(16) us Pb[32][264];  // normalized P (bf16)
  __shared__ float fred[32][2];             // cross-wave row max/sum exchange
  const int qr = (w >> 1) * 16, qc = (w & 1) * 32;
  const us* vb = vt + (long)z * 16384;
  const int ldr = tid >> 3, ldc = (tid & 7) << 3;

  for (int qi = 0; qi < 4; ++qi) {
    const int qb = half * 4 + qi;
    *(uint4*)&Qs[ldr][ldc] =
        *(const uint4*)(q + qkBase + (long)(qb * 32 + ldr) * 512 + ldc);
    f32x4 sacc[4][2] = {};
    for (int skb = 0; skb < 4; ++skb) {
      __syncthreads();  // Ks overwrite safe + Qs visible (skb==0)
      for (int i = tid; i < 512; i += 256) {
        int r = i >> 3, c = (i & 7) << 3;
        *(uint4*)&Ks[r][c] =
            *(const uint4*)(k + qkBase + (long)(skb * 64 + r) * 512 + c);
      }
      __syncthreads();
#pragma unroll
      for (int kh = 0; kh < 2; ++kh) {
        bf16x8 aq = *(const bf16x8*)&Qs[qr + lr][kh * 32 + lh * 8];
#pragma unroll
        for (int ni = 0; ni < 2; ++ni) {
          bf16x8 bkk = *(const bf16x8*)&Ks[qc + ni * 16 + lr][kh * 32 + lh * 8];
          sacc[skb][ni] = __builtin_amdgcn_mfma_f32_16x16x32_bf16(
              aq, bkk, sacc[skb][ni], 0, 0, 0);
        }
      }
    }
    // ---- softmax in registers ----
    float m0[4] = {-1e30f, -1e30f, -1e30f, -1e30f};
#pragma unroll
    for (int skb = 0; skb < 4; ++skb)
#pragma unroll
      for (int ni = 0; ni < 2; ++ni)
#pragma unroll
        for (int q_ = 0; q_ < 4; ++q_) {
          float v = sacc[skb][ni][q_] * 0.125f;
          sacc[skb][ni][q_] = v;
          m0[q_] = fmaxf(m0[q_], v);
        }
#pragma unroll
    for (int off = 1; off < 16; off <<= 1)
#pragma unroll
      for (int q_ = 0; q_ < 4; ++q_)
        m0[q_] = fmaxf(m0[q_], __shfl_xor(m0[q_], off));
    if (lr == 0) {
#pragma unroll
      for (int q_ = 0; q_ < 4; ++q_) fred[qr + lh * 4 + q_][w & 1] = m0[q_];
    }
    __syncthreads();
#pragma unroll
    for (int q_ = 0; q_ < 4; ++q_) {
      int row = qr + lh * 4 + q_;
      m0[q_] = fmaxf(fred[row][0], fred[row][1]);
    }
    float s0[4] = {0.f, 0.f, 0.f, 0.f};
#pragma unroll
    for (int skb = 0; skb < 4; ++skb)
#pragma unroll
      for (int ni = 0; ni < 2; ++ni)
#pragma unroll
        for (int q_ = 0; q_ < 4; ++q_) {
          float e = __expf(sacc[skb][ni][q_] - m0[q_]);
          sacc[skb][ni][q_] = e;
          s0[q_] += e;
        }
#pragma unroll
    for (int off = 1; off < 16; off <<= 1)
#pragma unroll
      for (int q_ = 0; q_ < 4; ++q_) s0[q_] += __shfl_xor(s0[q_], off);
    __syncthreads();  // max-reads of fred done before sum overwrite
    if (lr == 0) {
#pragma unroll
      for (int q_ = 0; q_ < 4; ++q_) fred[qr + lh * 4 + q_][w & 1] = s0[q_];
    }
    __syncthreads();
#pragma unroll
    for (int q_ = 0; q_ < 4; ++q_) {
      int row = qr + lh * 4 + q_;
      s0[q_] = 1.f / (fred[row][0] + fred[row][1]);
    }
    // normalized P -> LDS bf16
#pragma unroll
    for (int skb = 0; skb < 4; ++skb)
#pragma unroll
      for (int ni = 0; ni < 2; ++ni)
#pragma unroll
        for (int q_ = 0; q_ < 4; ++q_)
          Pb[qr + lh * 4 + q_][skb * 64 + qc + ni * 16 + lr] =
              f2bs(sacc[skb][ni][q_] * s0[q_]);
    // ---- PV: C[32 q][64 d] = P[32][256] x V[256][64] via V^T tiles ----
    f32x4 pacc[2] = {};
    for (int kc = 0; kc < 256; kc += 64) {
      __syncthreads();  // Pb visible (kc==0); prior Ks reads done
      for (int i = tid; i < 512; i += 256) {
        int r = i >> 3, c = (i & 7) << 3;
        *(uint4*)&Ks[r][c] = *(const uint4*)(vb + (long)r * 256 + kc + c);
      }
      __syncthreads();
#pragma unroll
      for (int kh = 0; kh < 2; ++kh) {
        bf16x8 ap = *(const bf16x8*)&Pb[qr + lr][kc + kh * 32 + lh * 8];
#pragma unroll
        for (int ni = 0; ni < 2; ++ni) {
          bf16x8 bv2 = *(const bf16x8*)&Ks[qc + ni * 16 + lr][kh * 32 + lh * 8];
          pacc[ni] = __builtin_amdgcn_mfma_f32_16x16x32_bf16(
              ap, bv2, pacc[ni], 0, 0, 0);
        }
      }
    }
    const long cb2 = ((long)(b * 256 + qb * 32)) * 512 + hh * 64;
#pragma unroll
    for (int ni = 0; ni < 2; ++ni)
#pragma unroll
      for (int q_ = 0; q_ < 4; ++q_) {
        int row = qr + lh * 4 + q_;
        int col = qc + ni * 16 + lr;
        ctx[cb2 + (long)row * 512 + col] = f2bs(pacc[ni][q_]);
      }
  }
}

// ---------------- BN stats / apply (bf16 y) ---------------------------------
__global__ __launch_bounds__(256) void bn_stats(const us* __restrict__ y,
                                                float* __restrict__ gsum,
                                                float* __restrict__ gsumsq) {
  int t = threadIdx.x;  // thread t owns columns 2t, 2t+1
  long base = (long)blockIdx.x * 64 * 512;
  float s0 = 0, q0 = 0, s1 = 0, q1 = 0;
  for (int r = 0; r < 64; ++r) {
    ushort2 v = *(const ushort2*)(y + base + r * 512 + 2 * t);
    float v0 = b2f(v.x), v1 = b2f(v.y);
    s0 += v0; q0 += v0 * v0;
    s1 += v1; q1 += v1 * v1;
  }
  atomicAdd(&gsum[2 * t], s0);
  atomicAdd(&gsumsq[2 * t], q0);
  atomicAdd(&gsum[2 * t + 1], s1);
  atomicAdd(&gsumsq[2 * t + 1], q1);
}

__global__ __launch_bounds__(256) void bn_apply(
    const us* __restrict__ y, const float* __restrict__ gsum,
    const float* __restrict__ gsumsq, const float* __restrict__ gamma,
    const float* __restrict__ beta, us* __restrict__ ybb) {
  long e = ((long)blockIdx.x * 256 + threadIdx.x) * 4;
  int c = (int)(e & 511);
  const float invN = 1.f / 16384.f;
  ushort4 v = *(const ushort4*)(y + e);
  ushort4 r;
#pragma unroll
  for (int j = 0; j < 4; ++j) {
    int cj = c + j;
    float mu = gsum[cj] * invN;
    float var = gsumsq[cj] * invN - mu * mu;
    float a = gamma[cj] * rsqrtf(var + BN_EPS);
    float b = beta[cj] - mu * a;
    ((us*)&r)[j] = f2bs(b2f(((us*)&v)[j]) * a + b);
  }
  *(ushort4*)(ybb + e) = r;
}

// ---------------- LayerNorm per row: zb (f32) -> hb (bf16) ------------------
__global__ __launch_bounds__(128) void ln_kernel(
    const float* __restrict__ zin, const float* __restrict__ g,
    const float* __restrict__ b, us* __restrict__ hb) {
  int r = blockIdx.x, t = threadIdx.x;
  const float* zr = zin + (long)r * 512;
  float4 v = *(const float4*)(zr + t * 4);
  float s = v.x + v.y + v.z + v.w;
  float qs = v.x * v.x + v.y * v.y + v.z * v.z + v.w * v.w;
  for (int off = 32; off >= 1; off >>= 1) {
    s += __shfl_down(s, off);
    qs += __shfl_down(qs, off);
  }
  __shared__ float ls[2], lq[2];
  if ((t & 63) == 0) {
    ls[t >> 6] = s;
    lq[t >> 6] = qs;
  }
  __syncthreads();
  float mu = (ls[0] + ls[1]) * (1.f / 512.f);
  float var = (lq[0] + lq[1]) * (1.f / 512.f) - mu * mu;
  float rs = rsqrtf(var + BN_EPS);
  float4 gg = *(const float4*)(g + t * 4);
  float4 bb = *(const float4*)(b + t * 4);
  ushort4 hv;
  ((us*)&hv)[0] = f2bs(gg.x * (v.x - mu) * rs + bb.x);
  ((us*)&hv)[1] = f2bs(gg.y * (v.y - mu) * rs + bb.y);
  ((us*)&hv)[2] = f2bs(gg.z * (v.z - mu) * rs + bb.z);
  ((us*)&hv)[3] = f2bs(gg.w * (v.w - mu) * rs + bb.w);
  *(ushort4*)(hb + (long)r * 512 + t * 4) = hv;
}

// ---------------- head ------------------------------------------------------
__global__ void zerof(float* __restrict__ p, int n) {
  int i = blockIdx.x * 256 + threadIdx.x;
  if (i < n) p[i] = 0.f;
}

__global__ __launch_bounds__(320) void final_head(
    const float* __restrict__ feat, const float* __restrict__ bf_,
    const float* __restrict__ action, const float* __restrict__ Wfin,
    const float* __restrict__ bfin, float* __restrict__ out) {
  int t = threadIdx.x;
  int b = t & 63, o = t >> 6;  // 64 x 5
  float acc = bfin[o];
  for (int j = 0; j < 32; ++j) acc += (feat[b * 32 + j] + bf_[j]) * Wfin[j * 5 + o];
  for (int j = 0; j < 8; ++j) acc += action[b * 8 + j] * Wfin[(32 + j) * 5 + o];
  out[b * 5 + o] = acc;
}

// ---------------- host ------------------------------------------------------
extern "C" void kernel_launch(void* const* d_in, const int* in_sizes, int n_in,
                              void* d_out, int out_size, void* d_ws,
                              size_t ws_size, hipStream_t stream) {
  const float* state = (const float*)d_in[0];
  const float* action = (const float*)d_in[1];
  const float* pes = (const float*)d_in[2];
  const float* W_emb = (const float*)d_in[3];
  const float* b_emb = (const float*)d_in[4];
  const float* Wq = (const float*)d_in[5];
  const float* bq = (const float*)d_in[6];
  const float* Wk = (const float*)d_in[7];
  const float* bk = (const float*)d_in[8];
  const float* Wv = (const float*)d_in[9];
  const float* bv = (const float*)d_in[10];
  const float* Wo = (const float*)d_in[11];
  const float* bo = (const float*)d_in[12];
  const float* bn_g = (const float*)d_in[13];
  const float* bn_b = (const float*)d_in[14];
  const float* W1 = (const float*)d_in[15];
  const float* b1 = (const float*)d_in[16];
  const float* W2 = (const float*)d_in[17];
  const float* b2 = (const float*)d_in[18];
  const float* ln_g = (const float*)d_in[19];
  const float* ln_b = (const float*)d_in[20];
  const float* Wf = (const float*)d_in[21];
  const float* bf_ = (const float*)d_in[22];
  const float* Wfin = (const float*)d_in[23];
  const float* bfin = (const float*)d_in[24];
  float* out = (float*)d_out;
  (void)in_sizes; (void)n_in; (void)out_size;

  char* wp = (char*)d_ws;
  size_t off = 0;
  auto take = [&](size_t bytes) {
    void* p = wp + off;
    off += (bytes + 255) & ~(size_t)255;
    return p;
  };
  // Persistent across the whole launch:
  us* qkvT = (us*)take(6ull * 1536 * 512 * 2);  // [l][{q,k,v}*512][512]
  us* WoT = (us*)take(6ull * 512 * 512 * 2);
  us* W1T = (us*)take(6ull * 2048 * 512 * 2);
  us* W2T = (us*)take(6ull * 512 * 2048 * 2);
  us* WfT = (us*)take(32ull * 131072 * 2);      // [32][131072]
  us* hb = (us*)take(16384ull * 512 * 2);        // bf16 trunk (LN output)
  us* ybf = (us*)take(16384ull * 512 * 2);       // bf16 y (attn-block out)
  // Aliased regions:
  //   R1: q -> z[0:8M)     R2: k -> y_bn(bf16) -> z[8M:16M)
  //   R3: vT               R4: ctx -> ffn hidden f1
  us* qb_ = (us*)take(16384ull * 512 * 2);       // R1
  us* kb_ = (us*)take(16384ull * 512 * 2);       // R2 (contiguous after R1)
  us* vt = (us*)take(16384ull * 512 * 2);        // R3
  us* bigR4 = (us*)take(33554432ull * 2);        // R4
  float* gsum = (float*)take(512 * 4);
  float* gsumsq = (float*)take(512 * 4);
  float* feat = (float*)take(2048 * 4);
  us* ctxb = bigR4;        // R4 (ctx live attn -> Wo)
  us* f1 = bigR4;          // R4 reuse (ctx dead after Wo)
  us* ybb = kb_;           // alias R2 (k dead after attn_kernel)
  float* zb = (float*)qb_; // alias R1+R2 (q dead after attn, ybb dead after FFN1)

  // Workspace guard: clean diagnostic failure instead of GPU fault.
  if (off > ws_size) return;

  transpose_bf16<<<dim3(16, 16, 6), 256, 0, stream>>>(Wq, qkvT, 512, 512,
                                                      262144, 786432);
  transpose_bf16<<<dim3(16, 16, 6), 256, 0, stream>>>(Wk, qkvT + 262144, 512,
                                                      512, 262144, 786432);
  transpose_bf16<<<dim3(16, 16, 6), 256, 0, stream>>>(Wv, qkvT + 524288, 512,
                                                      512, 262144, 786432);
  transpose_bf16<<<dim3(16, 16, 6), 256, 0, stream>>>(Wo, WoT, 512, 512,
                                                      262144, 262144);
  transpose_bf16<<<dim3(16, 64, 6), 256, 0, stream>>>(W1, W1T, 512, 2048,
                                                      1048576, 1048576);
  transpose_bf16<<<dim3(64, 16, 6), 256, 0, stream>>>(W2, W2T, 2048, 512,
                                                      1048576, 1048576);
  transpose_bf16<<<dim3(4096, 1, 1), 256, 0, stream>>>(Wf, WfT, 131072, 32,
                                                       0, 0);
  embed_kernel<<<2048, 256, 0, stream>>>(state, W_emb, b_emb, pes, hb);

  for (int l = 0; l < 6; ++l) {
    const us* qkvTl = qkvT + (size_t)l * 786432;
    const us* WoTl = WoT + (size_t)l * 262144;
    const us* W1Tl = W1T + (size_t)l * 1048576;
    const us* W2Tl = W2T + (size_t)l * 1048576;

    // fused QKV: N=1536, writes q, k, and v-transposed in one pass
    gemm_bt<128, 128, 64, 64, EPI_QKV><<<dim3(128, 12, 1), 256, 0, stream>>>(
        hb, 512, 0, qkvTl, 512, 0, qb_, kb_, vt, 512, bq + l * 512,
        nullptr, nullptr, nullptr, bk + l * 512, bv + l * 512, 512);
    // fused attention v2: QK^T + reg-softmax + PV -> ctx
    attn_kernel<<<dim3(2, 512), 256, 0, stream>>>(qb_, kb_, vt, ctxb);
    // Wo GEMM: y = ctx@Wo + bo + hb  (bf16 out, coalesced)
    gemm_bt<128, 128, 64, 64, EPI_RESID_BF16><<<dim3(128, 4, 1), 256, 0, stream>>>(
        ctxb, 512, 0, WoTl, 512, 0, ybf, nullptr, nullptr, 512, bo + l * 512,
        hb, nullptr, nullptr, nullptr, nullptr, 512);
    zerof<<<4, 256, 0, stream>>>(gsum, 1024);  // gsum+gsumsq contiguous
    bn_stats<<<256, 256, 0, stream>>>(ybf, gsum, gsumsq);
    bn_apply<<<8192, 256, 0, stream>>>(ybf, gsum, gsumsq, bn_g + l * 512,
                                       bn_b + l * 512, ybb);
    gemm_bt<128, 128, 64, 64, EPI_RELU_BF16><<<dim3(128, 16, 1), 256, 0, stream>>>(
        ybb, 512, 0, W1Tl, 512, 0, f1, nullptr, nullptr, 2048, b1 + l * 2048,
        nullptr, nullptr, nullptr, nullptr, nullptr, 512);
    gemm_bt<128, 128, 64, 64, EPI_FFN2_F32><<<dim3(128, 4, 1), 256, 0, stream>>>(
        f1, 2048, 0, W2Tl, 2048, 0, zb, nullptr, nullptr, 512, b2 + l * 512,
        ybf, gsum, gsumsq, bn_g + l * 512, bn_b + l * 512, 2048);
    ln_kernel<<<16384, 128, 0, stream>>>(zb, ln_g + l * 512, ln_b + l * 512, hb);
  }

  // feat = flat @ Wf: split-K over 128 chunks of 1024, fp32 atomic accumulate.
  zerof<<<8, 256, 0, stream>>>(feat, 2048);
  gemm_bt<64, 32, 32, 16, EPI_FEAT><<<dim3(1, 1, 128), 256, 0, stream>>>(
      hb, 131072, 1024, WfT, 131072, 1024, feat, nullptr, nullptr, 32,
      nullptr, nullptr, nullptr, nullptr, nullptr, nullptr, 1024);
  final_head<<<1, 320, 0, stream>>>(feat, bf_, action, Wfin, bfin, out);
}

// Round 10
// 1595.982 us; speedup vs baseline: 1.2690x; 1.0240x over previous
//
#include <hip/hip_runtime.h>

typedef short bf16x8 __attribute__((ext_vector_type(8)));
typedef float f32x4 __attribute__((ext_vector_type(4)));
typedef unsigned short us;

#define BN_EPS 1e-3f

// fp32 -> bf16 round-to-nearest-even (no NaN inputs in this net)
static __device__ __forceinline__ us f2bs(float x) {
  unsigned int u = __builtin_bit_cast(unsigned int, x);
  unsigned int r = (u + 0x7FFFu + ((u >> 16) & 1u)) >> 16;
  return (us)r;
}
static __device__ __forceinline__ float b2f(us v) {
  unsigned int u = (unsigned int)v << 16;
  return __builtin_bit_cast(float, u);
}

// async global->LDS, 16B per lane; LDS dest is wave-uniform base + lane*16.
static __device__ __forceinline__ void gl_lds16(const us* g, us* l) {
  __builtin_amdgcn_global_load_lds(
      (const __attribute__((address_space(1))) void*)g,
      (__attribute__((address_space(3))) void*)l, 16, 0, 0);
}

// ---------------- transpose + fp32->bf16: src [K,N] f32 -> dst [N,K] bf16 ----
__global__ __launch_bounds__(256) void transpose_bf16(
    const float* __restrict__ src, us* __restrict__ dst, int K, int N,
    long sstride, long dstride) {
  long sbs = (long)blockIdx.z * sstride;
  long sbd = (long)blockIdx.z * dstride;
  __shared__ float tile[32][33];
  int tx = threadIdx.x & 31, ty = threadIdx.x >> 5;  // 32 x 8
  int k0 = blockIdx.x * 32, n0 = blockIdx.y * 32;
  for (int i = 0; i < 32; i += 8)
    tile[ty + i][tx] = src[sbs + (long)(k0 + ty + i) * N + n0 + tx];
  __syncthreads();
  for (int i = 0; i < 32; i += 8)
    dst[sbd + (long)(n0 + ty + i) * K + k0 + tx] = f2bs(tile[tx][ty + i]);
}

// ---------------- embedding: hb = bf16(state @ Wemb + bemb + pes) -----------
__global__ __launch_bounds__(256) void embed_kernel(
    const float* __restrict__ state, const float* __restrict__ Wemb,
    const float* __restrict__ bemb, const float* __restrict__ pes,
    us* __restrict__ hb) {
  int t = threadIdx.x;
  int row0 = blockIdx.x * 8;
  __shared__ float st[8][64];
  {
    int i = t;
    st[i >> 6][i & 63] = state[(long)row0 * 64 + i];
    i += 256;
    st[i >> 6][i & 63] = state[(long)row0 * 64 + i];
  }
  __syncthreads();
  int c0 = t, c1 = t + 256;
  float acc0[8], acc1[8];
#pragma unroll
  for (int r = 0; r < 8; ++r) { acc0[r] = 0.f; acc1[r] = 0.f; }
  for (int kk = 0; kk < 64; ++kk) {
    float w0 = Wemb[kk * 512 + c0], w1 = Wemb[kk * 512 + c1];
#pragma unroll
    for (int r = 0; r < 8; ++r) {
      acc0[r] += st[r][kk] * w0;
      acc1[r] += st[r][kk] * w1;
    }
  }
  float be0 = bemb[c0], be1 = bemb[c1];
#pragma unroll
  for (int r = 0; r < 8; ++r) {
    int row = row0 + r, s = row & 255;
    hb[(long)row * 512 + c0] = f2bs(acc0[r] + be0 + pes[(long)s * 512 + c0]);
    hb[(long)row * 512 + c1] = f2bs(acc1[r] + be1 + pes[(long)s * 512 + c1]);
  }
}

// ---------------- generic bf16 MFMA GEMM, B given transposed [N,K] ----------
// Staging: global_load_lds width=16, linear LDS [BM][64] (BK=64), 2-barrier
// K-loop (m97 structure). 128x128 tile (R6 lesson). bf16 outputs staged
// through LDS for uint4 coalesced writes (R8). bf16 trunk (R9).
// R10: BN folded into W1 (bn_apply deleted); z carried bf16.
enum { EPI_QKV = 0, EPI_RESID_BF16 = 1, EPI_RELU_BF16 = 2, EPI_FFN2_BF16 = 3,
       EPI_FEAT = 4 };

template <int BM, int BN, int WM, int WN, int EPI>
__global__ __launch_bounds__((BM / WM) * (BN / WN) * 64)
void gemm_bt(const us* __restrict__ A, int lda, long batchA,
             const us* __restrict__ Bt, int ldb, long batchB,
             void* __restrict__ Cout, void* __restrict__ C2,
             void* __restrict__ C3, int ldc,
             const float* __restrict__ bias,
             const us* __restrict__ resid,
             const float* __restrict__ gsum, const float* __restrict__ gsumsq,
             const float* __restrict__ gamma, const float* __restrict__ beta,
             int K) {
  constexpr int WCols = BN / WN;
  constexpr int NT = (BM / WM) * (BN / WN) * 64;
  constexpr int NW = NT / 64;
  constexpr int MI = WM / 16, NI = WN / 16;
  constexpr int LA = BM / 8;  // 1KB wave-loads to fill A tile (8 rows each)
  constexpr int LB = BN / 8;
  const int tid = threadIdx.x;
  const int w = tid >> 6, l = tid & 63;
  const int wr = w / WCols, wc = w % WCols;
  const int lr = l & 15, lh = l >> 4;
  const int z = blockIdx.z;
  const long m0 = (long)blockIdx.x * BM;
  const long n0 = (long)blockIdx.y * BN;
  A += (long)z * batchA;
  Bt += (long)z * batchB;
  __shared__ __align__(16) us smem[BM * 64 + BN * 64];
  us* Asm = smem;            // [BM][64]
  us* Bsm = smem + BM * 64;  // [BN][64]
  const int srow = l >> 3, scol = (l & 7) << 3;
  f32x4 acc[MI][NI] = {};
  for (int kt = 0; kt < K; kt += 64) {
    __syncthreads();  // previous tile's reads complete before overwrite
    for (int j = w; j < LA; j += NW) {
      int rb = j * 8;
      gl_lds16(A + (m0 + rb + srow) * lda + kt + scol, Asm + rb * 64);
    }
    for (int j = w; j < LB; j += NW) {
      int rb = j * 8;
      gl_lds16(Bt + (n0 + rb + srow) * ldb + kt + scol, Bsm + rb * 64);
    }
    asm volatile("s_waitcnt vmcnt(0)" ::: "memory");
    __syncthreads();
#pragma unroll
    for (int kk = 0; kk < 64; kk += 32) {
      bf16x8 af[MI], bfr[NI];
#pragma unroll
      for (int mi = 0; mi < MI; ++mi)
        af[mi] = *(const bf16x8*)&Asm[(wr * WM + mi * 16 + lr) * 64 + kk + lh * 8];
#pragma unroll
      for (int ni = 0; ni < NI; ++ni)
        bfr[ni] = *(const bf16x8*)&Bsm[(wc * WN + ni * 16 + lr) * 64 + kk + lh * 8];
#pragma unroll
      for (int mi = 0; mi < MI; ++mi)
#pragma unroll
        for (int ni = 0; ni < NI; ++ni)
          acc[mi][ni] = __builtin_amdgcn_mfma_f32_16x16x32_bf16(
              af[mi], bfr[ni], acc[mi][ni], 0, 0, 0);
    }
  }

  if constexpr (EPI == EPI_QKV) {
    const int seg = (int)(n0 >> 9);  // uniform per block
    const int nc0 = (int)(n0 & 511);
    if (seg == 2) {
      // V^T: 4 consecutive s-rows contiguous -> ushort4
#pragma unroll
      for (int mi = 0; mi < MI; ++mi) {
#pragma unroll
        for (int ni = 0; ni < NI; ++ni) {
          const int segc = nc0 + wc * WN + ni * 16 + lr;
          const float bv_ = beta[segc];  // bv bias
          ushort4 pv;
#pragma unroll
          for (int q_ = 0; q_ < 4; ++q_)
            ((us*)&pv)[q_] = f2bs(acc[mi][ni][q_] + bv_);
          const long row0g = m0 + wr * WM + mi * 16 + lh * 4;
          const long o = (((row0g >> 8) * 8 + (segc >> 6)) * 64 + (segc & 63)) *
                             256 + (row0g & 255);
          *(ushort4*)&((us*)C3)[o] = pv;
        }
      }
    } else {
      // q/k: stage C-tile in LDS, coalesced uint4 writes
      __syncthreads();
#pragma unroll
      for (int mi = 0; mi < MI; ++mi)
#pragma unroll
        for (int ni = 0; ni < NI; ++ni) {
          const int cl = wc * WN + ni * 16 + lr;
          const float bv_ = seg == 0 ? bias[nc0 + cl] : gamma[nc0 + cl];
#pragma unroll
          for (int q_ = 0; q_ < 4; ++q_) {
            const int rl = wr * WM + mi * 16 + lh * 4 + q_;
            smem[rl * BN + cl] = f2bs(acc[mi][ni][q_] + bv_);
          }
        }
      __syncthreads();
      us* dstp = seg == 0 ? (us*)Cout : (us*)C2;
      for (int i = tid; i < (BM * BN) / 8; i += NT) {
        const int idx = i * 8;
        const int row = idx / BN, colc = idx % BN;
        *(uint4*)&dstp[(m0 + row) * 512 + nc0 + colc] = *(uint4*)&smem[idx];
      }
    }
  } else if constexpr ((EPI == EPI_RELU_BF16 || EPI == EPI_RESID_BF16 ||
                        EPI == EPI_FFN2_BF16) && BM == 128 && BN == 128) {
    // bf16 output staged through LDS for coalesced writes
    __syncthreads();
#pragma unroll
    for (int mi = 0; mi < MI; ++mi)
#pragma unroll
      for (int ni = 0; ni < NI; ++ni) {
        const int cl = wc * WN + ni * 16 + lr;
        const int col = (int)n0 + cl;
        const float bv_ = bias[col];
        float aa = 0.f, bb2 = 0.f;
        if constexpr (EPI == EPI_FFN2_BF16) {
          aa = gsum[col];    // pre-baked BN scale (bn_coef)
          bb2 = gsumsq[col]; // pre-baked BN shift
        }
#pragma unroll
        for (int q_ = 0; q_ < 4; ++q_) {
          const int rl = wr * WM + mi * 16 + lh * 4 + q_;
          float v = acc[mi][ni][q_] + bv_;
          if constexpr (EPI == EPI_RELU_BF16) {
            smem[rl * BN + cl] = f2bs(fmaxf(v, 0.f));
          } else if constexpr (EPI == EPI_RESID_BF16) {
            v += b2f(resid[(m0 + rl) * ldc + col]);
            smem[rl * BN + cl] = f2bs(v);
          } else {  // FFN2: z = (a*y+b) + acc + bias, bf16 out
            float ybn = b2f(resid[(m0 + rl) * ldc + col]) * aa + bb2;
            smem[rl * BN + cl] = f2bs(ybn + v);
          }
        }
      }
    __syncthreads();
    for (int i = tid; i < (BM * BN) / 8; i += NT) {
      const int idx = i * 8;
      const int row = idx / BN, colc = idx % BN;
      *(uint4*)&((us*)Cout)[(m0 + row) * ldc + n0 + colc] = *(uint4*)&smem[idx];
    }
  } else {
    // f32 epilogues (feat atomics)
#pragma unroll
    for (int mi = 0; mi < MI; ++mi) {
#pragma unroll
      for (int ni = 0; ni < NI; ++ni) {
        const int col = (int)n0 + wc * WN + ni * 16 + lr;
#pragma unroll
        for (int q_ = 0; q_ < 4; ++q_) {
          const long row = m0 + wr * WM + mi * 16 + lh * 4 + q_;
          if constexpr (EPI == EPI_FEAT) {
            atomicAdd(&((float*)Cout)[row * ldc + col], acc[mi][ni][q_]);
          }
        }
      }
    }
  }
}

// ---------------- fused attention v2: QK^T*scale + reg-softmax + PV ---------
// grid (2, B*H): each block owns one (b,h) half — 4 q-tiles of 32 rows.
__global__ __launch_bounds__(256) void attn_kernel(
    const us* __restrict__ q, const us* __restrict__ k,
    const us* __restrict__ vt, us* __restrict__ ctx) {
  const int half = blockIdx.x;  // 0..1
  const int z = blockIdx.y;     // b*8+h
  const int b = z >> 3, hh = z & 7;
  const long qkBase = (long)b * 131072 + hh * 64;
  const int tid = threadIdx.x, w = tid >> 6, l = tid & 63;
  const int lr = l & 15, lh = l >> 4;
  __shared__ __align__(16) us Qs[32][72];
  __shared__ __align__(16) us Ks[64][72];   // K chunk, reused for V chunks
  __shared__ __align__(16) us Pb[32][264];  // normalized P (bf16)
  __shared__ float fred[32][2];             // cross-wave row max/sum exchange
  const int qr = (w >> 1) * 16, qc = (w & 1) * 32;
  const us* vb = vt + (long)z * 16384;
  const int ldr = tid >> 3, ldc = (tid & 7) << 3;

  for (int qi = 0; qi < 4; ++qi) {
    const int qb = half * 4 + qi;
    *(uint4*)&Qs[ldr][ldc] =
        *(const uint4*)(q + qkBase + (long)(qb * 32 + ldr) * 512 + ldc);
    f32x4 sacc[4][2] = {};
    for (int skb = 0; skb < 4; ++skb) {
      __syncthreads();  // Ks overwrite safe + Qs visible (skb==0)
      for (int i = tid; i < 512; i += 256) {
        int r = i >> 3, c = (i & 7) << 3;
        *(uint4*)&Ks[r][c] =
            *(const uint4*)(k + qkBase + (long)(skb * 64 + r) * 512 + c);
      }
      __syncthreads();
#pragma unroll
      for (int kh = 0; kh < 2; ++kh) {
        bf16x8 aq = *(const bf16x8*)&Qs[qr + lr][kh * 32 + lh * 8];
#pragma unroll
        for (int ni = 0; ni < 2; ++ni) {
          bf16x8 bkk = *(const bf16x8*)&Ks[qc + ni * 16 + lr][kh * 32 + lh * 8];
          sacc[skb][ni] = __builtin_amdgcn_mfma_f32_16x16x32_bf16(
              aq, bkk, sacc[skb][ni], 0, 0, 0);
        }
      }
    }
    // ---- softmax in registers ----
    float m0[4] = {-1e30f, -1e30f, -1e30f, -1e30f};
#pragma unroll
    for (int skb = 0; skb < 4; ++skb)
#pragma unroll
      for (int ni = 0; ni < 2; ++ni)
#pragma unroll
        for (int q_ = 0; q_ < 4; ++q_) {
          float v = sacc[skb][ni][q_] * 0.125f;
          sacc[skb][ni][q_] = v;
          m0[q_] = fmaxf(m0[q_], v);
        }
#pragma unroll
    for (int off = 1; off < 16; off <<= 1)
#pragma unroll
      for (int q_ = 0; q_ < 4; ++q_)
        m0[q_] = fmaxf(m0[q_], __shfl_xor(m0[q_], off));
    if (lr == 0) {
#pragma unroll
      for (int q_ = 0; q_ < 4; ++q_) fred[qr + lh * 4 + q_][w & 1] = m0[q_];
    }
    __syncthreads();
#pragma unroll
    for (int q_ = 0; q_ < 4; ++q_) {
      int row = qr + lh * 4 + q_;
      m0[q_] = fmaxf(fred[row][0], fred[row][1]);
    }
    float s0[4] = {0.f, 0.f, 0.f, 0.f};
#pragma unroll
    for (int skb = 0; skb < 4; ++skb)
#pragma unroll
      for (int ni = 0; ni < 2; ++ni)
#pragma unroll
        for (int q_ = 0; q_ < 4; ++q_) {
          float e = __expf(sacc[skb][ni][q_] - m0[q_]);
          sacc[skb][ni][q_] = e;
          s0[q_] += e;
        }
#pragma unroll
    for (int off = 1; off < 16; off <<= 1)
#pragma unroll
      for (int q_ = 0; q_ < 4; ++q_) s0[q_] += __shfl_xor(s0[q_], off);
    __syncthreads();  // max-reads of fred done before sum overwrite
    if (lr == 0) {
#pragma unroll
      for (int q_ = 0; q_ < 4; ++q_) fred[qr + lh * 4 + q_][w & 1] = s0[q_];
    }
    __syncthreads();
#pragma unroll
    for (int q_ = 0; q_ < 4; ++q_) {
      int row = qr + lh * 4 + q_;
      s0[q_] = 1.f / (fred[row][0] + fred[row][1]);
    }
    // normalized P -> LDS bf16
#pragma unroll
    for (int skb = 0; skb < 4; ++skb)
#pragma unroll
      for (int ni = 0; ni < 2; ++ni)
#pragma unroll
        for (int q_ = 0; q_ < 4; ++q_)
          Pb[qr + lh * 4 + q_][skb * 64 + qc + ni * 16 + lr] =
              f2bs(sacc[skb][ni][q_] * s0[q_]);
    // ---- PV: C[32 q][64 d] = P[32][256] x V[256][64] via V^T tiles ----
    f32x4 pacc[2] = {};
    for (int kc = 0; kc < 256; kc += 64) {
      __syncthreads();  // Pb visible (kc==0); prior Ks reads done
      for (int i = tid; i < 512; i += 256) {
        int r = i >> 3, c = (i & 7) << 3;
        *(uint4*)&Ks[r][c] = *(const uint4*)(vb + (long)r * 256 + kc + c);
      }
      __syncthreads();
#pragma unroll
      for (int kh = 0; kh < 2; ++kh) {
        bf16x8 ap = *(const bf16x8*)&Pb[qr + lr][kc + kh * 32 + lh * 8];
#pragma unroll
        for (int ni = 0; ni < 2; ++ni) {
          bf16x8 bv2 = *(const bf16x8*)&Ks[qc + ni * 16 + lr][kh * 32 + lh * 8];
          pacc[ni] = __builtin_amdgcn_mfma_f32_16x16x32_bf16(
              ap, bv2, pacc[ni], 0, 0, 0);
        }
      }
    }
    const long cb2 = ((long)(b * 256 + qb * 32)) * 512 + hh * 64;
#pragma unroll
    for (int ni = 0; ni < 2; ++ni)
#pragma unroll
      for (int q_ = 0; q_ < 4; ++q_) {
        int row = qr + lh * 4 + q_;
        int col = qc + ni * 16 + lr;
        ctx[cb2 + (long)row * 512 + col] = f2bs(pacc[ni][q_]);
      }
  }
}

// ---------------- BN stats (bf16 y) -----------------------------------------
__global__ __launch_bounds__(256) void bn_stats(const us* __restrict__ y,
                                                float* __restrict__ gsum,
                                                float* __restrict__ gsumsq) {
  int t = threadIdx.x;  // thread t owns columns 2t, 2t+1
  long base = (long)blockIdx.x * 64 * 512;
  float s0 = 0, q0 = 0, s1 = 0, q1 = 0;
  for (int r = 0; r < 64; ++r) {
    ushort2 v = *(const ushort2*)(y + base + r * 512 + 2 * t);
    float v0 = b2f(v.x), v1 = b2f(v.y);
    s0 += v0; q0 += v0 * v0;
    s1 += v1; q1 += v1 * v1;
  }
  atomicAdd(&gsum[2 * t], s0);
  atomicAdd(&gsumsq[2 * t], q0);
  atomicAdd(&gsum[2 * t + 1], s1);
  atomicAdd(&gsumsq[2 * t + 1], q1);
}

// bn_coef: gsum/gsumsq -> (a, b) in place: a = g*rsqrt(var+eps), b = beta-mu*a
__global__ void bn_coef(float* __restrict__ gsum, float* __restrict__ gsumsq,
                        const float* __restrict__ gamma,
                        const float* __restrict__ beta) {
  int c = blockIdx.x * 256 + threadIdx.x;
  if (c < 512) {
    const float invN = 1.f / 16384.f;
    float mu = gsum[c] * invN;
    float var = gsumsq[c] * invN - mu * mu;
    float a = gamma[c] * rsqrtf(var + BN_EPS);
    float b = beta[c] - mu * a;
    gsum[c] = a;
    gsumsq[c] = b;
  }
}

// fold_w1: W1s[n][k] = bf16(a_k * W1T[n][k]); bias1f[n] = b1[n] + sum_k b_k*W1T[n][k]
__global__ __launch_bounds__(256) void fold_w1(
    const us* __restrict__ W1T, const float* __restrict__ aa,
    const float* __restrict__ bb, const float* __restrict__ b1,
    us* __restrict__ W1s, float* __restrict__ bias1f) {
  int n = blockIdx.x * 4 + (threadIdx.x >> 6);  // one wave per output row
  int l = threadIdx.x & 63;
  int k0 = l * 8;
  const us* row = W1T + (long)n * 512;
  us tmp[8], outv[8];
  *(uint4*)tmp = *(const uint4*)(row + k0);
  float dot = 0.f;
#pragma unroll
  for (int j = 0; j < 8; ++j) {
    float wv = b2f(tmp[j]);
    dot += bb[k0 + j] * wv;
    outv[j] = f2bs(aa[k0 + j] * wv);
  }
  *(uint4*)(W1s + (long)n * 512 + k0) = *(uint4*)outv;
  for (int off = 32; off >= 1; off >>= 1) dot += __shfl_down(dot, off);
  if (l == 0) bias1f[n] = b1[n] + dot;
}

// ---------------- LayerNorm per row: zbf (bf16) -> hb (bf16) ----------------
__global__ __launch_bounds__(128) void ln_kernel(
    const us* __restrict__ zin, const float* __restrict__ g,
    const float* __restrict__ b, us* __restrict__ hb) {
  int r = blockIdx.x, t = threadIdx.x;
  const us* zr = zin + (long)r * 512;
  ushort4 vz = *(const ushort4*)(zr + t * 4);
  float v0 = b2f(((us*)&vz)[0]), v1 = b2f(((us*)&vz)[1]);
  float v2 = b2f(((us*)&vz)[2]), v3 = b2f(((us*)&vz)[3]);
  float s = v0 + v1 + v2 + v3;
  float qs = v0 * v0 + v1 * v1 + v2 * v2 + v3 * v3;
  for (int off = 32; off >= 1; off >>= 1) {
    s += __shfl_down(s, off);
    qs += __shfl_down(qs, off);
  }
  __shared__ float ls[2], lq[2];
  if ((t & 63) == 0) {
    ls[t >> 6] = s;
    lq[t >> 6] = qs;
  }
  __syncthreads();
  float mu = (ls[0] + ls[1]) * (1.f / 512.f);
  float var = (lq[0] + lq[1]) * (1.f / 512.f) - mu * mu;
  float rs = rsqrtf(var + BN_EPS);
  float4 gg = *(const float4*)(g + t * 4);
  float4 bb = *(const float4*)(b + t * 4);
  ushort4 hv;
  ((us*)&hv)[0] = f2bs(gg.x * (v0 - mu) * rs + bb.x);
  ((us*)&hv)[1] = f2bs(gg.y * (v1 - mu) * rs + bb.y);
  ((us*)&hv)[2] = f2bs(gg.z * (v2 - mu) * rs + bb.z);
  ((us*)&hv)[3] = f2bs(gg.w * (v3 - mu) * rs + bb.w);
  *(ushort4*)(hb + (long)r * 512 + t * 4) = hv;
}

// ---------------- head ------------------------------------------------------
__global__ void zerof(float* __restrict__ p, int n) {
  int i = blockIdx.x * 256 + threadIdx.x;
  if (i < n) p[i] = 0.f;
}

__global__ __launch_bounds__(320) void final_head(
    const float* __restrict__ feat, const float* __restrict__ bf_,
    const float* __restrict__ action, const float* __restrict__ Wfin,
    const float* __restrict__ bfin, float* __restrict__ out) {
  int t = threadIdx.x;
  int b = t & 63, o = t >> 6;  // 64 x 5
  float acc = bfin[o];
  for (int j = 0; j < 32; ++j) acc += (feat[b * 32 + j] + bf_[j]) * Wfin[j * 5 + o];
  for (int j = 0; j < 8; ++j) acc += action[b * 8 + j] * Wfin[(32 + j) * 5 + o];
  out[b * 5 + o] = acc;
}

// ---------------- host ------------------------------------------------------
extern "C" void kernel_launch(void* const* d_in, const int* in_sizes, int n_in,
                              void* d_out, int out_size, void* d_ws,
                              size_t ws_size, hipStream_t stream) {
  const float* state = (const float*)d_in[0];
  const float* action = (const float*)d_in[1];
  const float* pes = (const float*)d_in[2];
  const float* W_emb = (const float*)d_in[3];
  const float* b_emb = (const float*)d_in[4];
  const float* Wq = (const float*)d_in[5];
  const float* bq = (const float*)d_in[6];
  const float* Wk = (const float*)d_in[7];
  const float* bk = (const float*)d_in[8];
  const float* Wv = (const float*)d_in[9];
  const float* bv = (const float*)d_in[10];
  const float* Wo = (const float*)d_in[11];
  const float* bo = (const float*)d_in[12];
  const float* bn_g = (const float*)d_in[13];
  const float* bn_b = (const float*)d_in[14];
  const float* W1 = (const float*)d_in[15];
  const float* b1 = (const float*)d_in[16];
  const float* W2 = (const float*)d_in[17];
  const float* b2 = (const float*)d_in[18];
  const float* ln_g = (const float*)d_in[19];
  const float* ln_b = (const float*)d_in[20];
  const float* Wf = (const float*)d_in[21];
  const float* bf_ = (const float*)d_in[22];
  const float* Wfin = (const float*)d_in[23];
  const float* bfin = (const float*)d_in[24];
  float* out = (float*)d_out;
  (void)in_sizes; (void)n_in; (void)out_size;

  char* wp = (char*)d_ws;
  size_t off = 0;
  auto take = [&](size_t bytes) {
    void* p = wp + off;
    off += (bytes + 255) & ~(size_t)255;
    return p;
  };
  // Persistent across the whole launch:
  us* qkvT = (us*)take(6ull * 1536 * 512 * 2);  // [l][{q,k,v}*512][512]
  us* WoT = (us*)take(6ull * 512 * 512 * 2);
  us* W1T = (us*)take(6ull * 2048 * 512 * 2);
  us* W2T = (us*)take(6ull * 512 * 2048 * 2);
  us* WfT = (us*)take(32ull * 131072 * 2);      // [32][131072]
  us* hb = (us*)take(16384ull * 512 * 2);        // bf16 trunk (LN output)
  us* ybf = (us*)take(16384ull * 512 * 2);       // bf16 y (attn-block out)
  us* W1s = (us*)take(2048ull * 512 * 2);        // BN-folded W1 (per layer)
  float* bias1f = (float*)take(2048 * 4);        // folded FFN1 bias
  // Aliased regions:
  //   R1: q -> zbf      R2: k      R3: vT      R4: ctx -> ffn hidden f1
  us* qb_ = (us*)take(16384ull * 512 * 2);       // R1
  us* kb_ = (us*)take(16384ull * 512 * 2);       // R2
  us* vt = (us*)take(16384ull * 512 * 2);        // R3
  us* bigR4 = (us*)take(33554432ull * 2);        // R4
  float* gsum = (float*)take(512 * 4);
  float* gsumsq = (float*)take(512 * 4);
  float* feat = (float*)take(2048 * 4);
  us* ctxb = bigR4;   // R4 (ctx live attn -> Wo)
  us* f1 = bigR4;     // R4 reuse (ctx dead after Wo)
  us* zbf = qb_;      // alias R1 (q dead after attn; zbf dead after ln,
                      //           before next layer's QKV writes q)

  // Workspace guard: clean diagnostic failure instead of GPU fault.
  if (off > ws_size) return;

  transpose_bf16<<<dim3(16, 16, 6), 256, 0, stream>>>(Wq, qkvT, 512, 512,
                                                      262144, 786432);
  transpose_bf16<<<dim3(16, 16, 6), 256, 0, stream>>>(Wk, qkvT + 262144, 512,
                                                      512, 262144, 786432);
  transpose_bf16<<<dim3(16, 16, 6), 256, 0, stream>>>(Wv, qkvT + 524288, 512,
                                                      512, 262144, 786432);
  transpose_bf16<<<dim3(16, 16, 6), 256, 0, stream>>>(Wo, WoT, 512, 512,
                                                      262144, 262144);
  transpose_bf16<<<dim3(16, 64, 6), 256, 0, stream>>>(W1, W1T, 512, 2048,
                                                      1048576, 1048576);
  transpose_bf16<<<dim3(64, 16, 6), 256, 0, stream>>>(W2, W2T, 2048, 512,
                                                      1048576, 1048576);
  transpose_bf16<<<dim3(4096, 1, 1), 256, 0, stream>>>(Wf, WfT, 131072, 32,
                                                       0, 0);
  embed_kernel<<<2048, 256, 0, stream>>>(state, W_emb, b_emb, pes, hb);

  for (int l = 0; l < 6; ++l) {
    const us* qkvTl = qkvT + (size_t)l * 786432;
    const us* WoTl = WoT + (size_t)l * 262144;
    const us* W1Tl = W1T + (size_t)l * 1048576;
    const us* W2Tl = W2T + (size_t)l * 1048576;

    // fused QKV: N=1536, writes q, k, and v-transposed in one pass
    gemm_bt<128, 128, 64, 64, EPI_QKV><<<dim3(128, 12, 1), 256, 0, stream>>>(
        hb, 512, 0, qkvTl, 512, 0, qb_, kb_, vt, 512, bq + l * 512,
        nullptr, nullptr, nullptr, bk + l * 512, bv + l * 512, 512);
    // fused attention v2: QK^T + reg-softmax + PV -> ctx
    attn_kernel<<<dim3(2, 512), 256, 0, stream>>>(qb_, kb_, vt, ctxb);
    // Wo GEMM: y = ctx@Wo + bo + hb  (bf16 out, coalesced)
    gemm_bt<128, 128, 64, 64, EPI_RESID_BF16><<<dim3(128, 4, 1), 256, 0, stream>>>(
        ctxb, 512, 0, WoTl, 512, 0, ybf, nullptr, nullptr, 512, bo + l * 512,
        hb, nullptr, nullptr, nullptr, nullptr, 512);
    zerof<<<4, 256, 0, stream>>>(gsum, 1024);  // gsum+gsumsq contiguous
    bn_stats<<<256, 256, 0, stream>>>(ybf, gsum, gsumsq);
    bn_coef<<<2, 256, 0, stream>>>(gsum, gsumsq, bn_g + l * 512,
                                   bn_b + l * 512);
    // fold BN into W1: W1s = a∘W1, bias1f = b1 + b·W1
    fold_w1<<<512, 256, 0, stream>>>(W1Tl, gsum, gsumsq, b1 + l * 2048, W1s,
                                     bias1f);
    // FFN1 reads ybf directly (BN folded into weights)
    gemm_bt<128, 128, 64, 64, EPI_RELU_BF16><<<dim3(128, 16, 1), 256, 0, stream>>>(
        ybf, 512, 0, W1s, 512, 0, f1, nullptr, nullptr, 2048, bias1f,
        nullptr, nullptr, nullptr, nullptr, nullptr, 512);
    // FFN2: z = (a*y+b) + f1@W2 + b2  (bf16 out, coalesced)
    gemm_bt<128, 128, 64, 64, EPI_FFN2_BF16><<<dim3(128, 4, 1), 256, 0, stream>>>(
        f1, 2048, 0, W2Tl, 2048, 0, zbf, nullptr, nullptr, 512, b2 + l * 512,
        ybf, gsum, gsumsq, nullptr, nullptr, 2048);
    ln_kernel<<<16384, 128, 0, stream>>>(zbf, ln_g + l * 512, ln_b + l * 512,
                                         hb);
  }

  // feat = flat @ Wf: split-K over 128 chunks of 1024, fp32 atomic accumulate.
  zerof<<<8, 256, 0, stream>>>(feat, 2048);
  gemm_bt<64, 32, 32, 16, EPI_FEAT><<<dim3(1, 1, 128), 256, 0, stream>>>(
      hb, 131072, 1024, WfT, 131072, 1024, feat, nullptr, nullptr, 32,
      nullptr, nullptr, nullptr, nullptr, nullptr, nullptr, 1024);
  final_head<<<1, 320, 0, stream>>>(feat, bf_, action, Wfin, bfin, out);
}